// Round 1
// baseline (226072.388 us; speedup 1.0000x reference)
//
#include <hip/hip_runtime.h>
#include <hip/hip_cooperative_groups.h>

namespace cg = cooperative_groups;

#define TT 512
#define BB 256
#define DD 128
#define HH 512
#define KA 1152   // 512 (h1) + 512 (h2) + 128 (x)
#define KB 1024   // 512 (h2) + 512 (h1new)

// ---- workspace layout (float offsets) ----
#define O_WP1 0u
#define N_WP1 (512u*KA*4u)            // [nb][k][4] packed layer-1 weights
#define O_WP2 (O_WP1 + N_WP1)
#define N_WP2 (512u*KB*4u)
#define O_WZ1 (O_WP2 + N_WP2)         // z-row layer 1 (KA)
#define O_WZ2 (O_WZ1 + KA)            // z-row layer 2 (KB)
#define O_BP1 (O_WZ2 + KB)            // permuted bias l1 (2048)
#define O_BP2 (O_BP1 + 2048u)         // permuted bias l2 (2048)
#define O_BZ  (O_BP2 + 2048u)         // bz1, bz2, pad, pad
#define O_H1  (O_BZ + 4u)             // h1 ping-pong [2][256][512]
#define N_H   (2u*BB*HH)
#define O_H2  (O_H1 + N_H)
#define N_TOT (O_H2 + N_H)

static_assert((O_H1 % 4u) == 0u, "h1 alignment");

// Pack weights: output column c (0..2047) corresponds to source row
// n = (c&3)*512 + (c>>2)  (gate-interleaved so each 32-col tile owns
// 8 complete hidden units with their f,i,o,g rows).
// Wp layout: [nb = c>>2][k][j = c&3], so per k one float4 = 4 gate rows.
__global__ void pack_kernel(const float* __restrict__ U11_1, const float* __restrict__ U21_1,
                            const float* __restrict__ W01_1, const float* __restrict__ b1,
                            const float* __restrict__ U11_2, const float* __restrict__ W01_2,
                            const float* __restrict__ b2, float* __restrict__ ws) {
  unsigned i = blockIdx.x * 256u + threadIdx.x;
  if (i >= N_TOT) return;
  float v = 0.f;
  if (i < O_WP2) {                         // Wp1
    unsigned r = i - O_WP1;
    unsigned nb = r / (KA*4u);
    unsigned q  = r % (KA*4u);
    unsigned k = q >> 2, j = q & 3u;
    unsigned n = j*512u + nb;
    v = (k < 512u)  ? U11_1[n*512u + k]
      : (k < 1024u) ? U21_1[n*512u + (k-512u)]
                    : W01_1[n*128u + (k-1024u)];
  } else if (i < O_WZ1) {                  // Wp2
    unsigned r = i - O_WP2;
    unsigned nb = r / (KB*4u);
    unsigned q  = r % (KB*4u);
    unsigned k = q >> 2, j = q & 3u;
    unsigned n = j*512u + nb;
    v = (k < 512u) ? U11_2[n*512u + k]
                   : W01_2[n*512u + (k-512u)];
  } else if (i < O_WZ2) {                  // z-row layer 1
    unsigned k = i - O_WZ1;
    v = (k < 512u)  ? U11_1[2048u*512u + k]
      : (k < 1024u) ? U21_1[2048u*512u + (k-512u)]
                    : W01_1[2048u*128u + (k-1024u)];
  } else if (i < O_BP1) {                  // z-row layer 2
    unsigned k = i - O_WZ2;
    v = (k < 512u) ? U11_2[2048u*512u + k]
                   : W01_2[2048u*512u + (k-512u)];
  } else if (i < O_BP2) {                  // bias l1 permuted
    unsigned c = i - O_BP1;
    v = b1[(c & 3u)*512u + (c >> 2)];
  } else if (i < O_BZ) {                   // bias l2 permuted
    unsigned c = i - O_BP2;
    v = b2[(c & 3u)*512u + (c >> 2)];
  } else if (i == O_BZ)     v = b1[2048];
  else if (i == O_BZ + 1u)  v = b2[2048];
  else                      v = 0.f;       // padding + zero h1/h2 state buffers
  ws[i] = v;
}

__device__ __forceinline__ float sigmoidf_(float x) { return 1.f / (1.f + __expf(-x)); }

#define FMA16(a, wb, kidx, Q0, Q1, Q2, Q3) {                                     \
    float4 w0_ = (wb)[(kidx)];   float4 w1_ = (wb)[(kidx)+1];                    \
    float4 w2_ = (wb)[(kidx)+2]; float4 w3_ = (wb)[(kidx)+3];                    \
    Q0 = fmaf((a).x, w0_.x, Q0); Q1 = fmaf((a).x, w0_.y, Q1);                    \
    Q2 = fmaf((a).x, w0_.z, Q2); Q3 = fmaf((a).x, w0_.w, Q3);                    \
    Q0 = fmaf((a).y, w1_.x, Q0); Q1 = fmaf((a).y, w1_.y, Q1);                    \
    Q2 = fmaf((a).y, w1_.z, Q2); Q3 = fmaf((a).y, w1_.w, Q3);                    \
    Q0 = fmaf((a).z, w2_.x, Q0); Q1 = fmaf((a).z, w2_.y, Q1);                    \
    Q2 = fmaf((a).z, w2_.z, Q2); Q3 = fmaf((a).z, w2_.w, Q3);                    \
    Q0 = fmaf((a).w, w3_.x, Q0); Q1 = fmaf((a).w, w3_.y, Q1);                    \
    Q2 = fmaf((a).w, w3_.z, Q2); Q3 = fmaf((a).w, w3_.w, Q3); }

// Persistent cooperative kernel: 256 WGs x 512 threads.
// WG = (mg: 64 batch rows) x (ntile: 32 cols = 8 hidden units x 4 gates).
// wave (8 per WG) = 64 rows (lane = row) x 4 cols; wave-uniform weight loads.
__global__ __launch_bounds__(512) void hmlstm_kernel(const float* __restrict__ x,
                                                     float* __restrict__ ws,
                                                     float* __restrict__ y) {
  cg::grid_group grid = cg::this_grid();
  const int tid  = threadIdx.x;
  const int lane = tid & 63;
  const int nw   = tid >> 6;           // wave id 0..7
  const int bid  = blockIdx.x;
  const int mg    = bid & 3;           // M-group (same-mg WGs land on few XCDs)
  const int ntile = bid >> 2;          // 0..63
  const int b0 = mg * 64;
  const int c0 = ntile * 32;
  const int j0 = ntile * 8;

  const float* Wp1 = ws + O_WP1;
  const float* Wp2 = ws + O_WP2;
  const float* wz1 = ws + O_WZ1;
  const float* wz2 = ws + O_WZ2;
  const float* bp1 = ws + O_BP1;
  const float* bp2 = ws + O_BP2;
  const float  bz1 = ws[O_BZ], bz2 = ws[O_BZ + 1u];
  float* h1g = ws + O_H1;
  float* h2g = ws + O_H2;

  __shared__ float ls_s[64][36];
  __shared__ float zred[8][64];
  __shared__ float c1s[64][8], c2s[64][8], h2loc[64][8];
  __shared__ float z1s[64], z2s[64], z1n[64], z2n[64];

  { int b = tid >> 3, u = tid & 7;
    c1s[b][u] = 0.f; c2s[b][u] = 0.f; h2loc[b][u] = 0.f; }
  if (tid < 64) { z1s[tid] = 0.f; z2s[tid] = 0.f; z1n[tid] = 0.f; z2n[tid] = 0.f; }
  __syncthreads();

  const int nbu = __builtin_amdgcn_readfirstlane(ntile * 8 + nw);
  const float4* w41 = (const float4*)(Wp1 + (size_t)nbu * (KA * 4u));
  const float4* w42 = (const float4*)(Wp2 + (size_t)nbu * (KB * 4u));
  const int row = b0 + lane;
  const int eb = tid >> 3, eu = tid & 7;  // epilogue mapping: (batch row, unit)

  int p = 0;
  for (int t = 0; t < TT; ++t) {
    const float* h1rd = h1g + p * (BB * HH);
    float*       h1wr = h1g + (p ^ 1) * (BB * HH);
    const float* h2rd = h2g + p * (BB * HH);
    float*       h2wr = h2g + (p ^ 1) * (BB * HH);

    // ================= PHASE A (layer 1) =================
    if (tid < 64) z1s[tid] = z1n[tid];   // z1(t-1) becomes current
    __syncthreads();

    if (t > 0) {  // y(t-1) = h2(t-1) * z2(t-1)
      y[((size_t)(b0 + eb) * TT + (t - 1)) * HH + j0 + eu] = h2loc[eb][eu] * z2n[eb];
    }

    {
      const float* a1 = h1rd + row * HH;
      const float* a2 = h2rd + row * HH;
      const float* ax = x + (size_t)row * (TT * DD) + t * DD;
      const float sc1 = 1.f - z1s[lane];
      const float sc2 = z1s[lane];
      const float4* a14 = (const float4*)a1;
      const float4* a24 = (const float4*)a2;
      const float4* ax4 = (const float4*)ax;
      float A0=0,A1=0,A2=0,A3=0, B0=0,B1=0,B2=0,B3=0, X0=0,X1=0,X2=0,X3=0;
      #pragma unroll 2
      for (int k4 = 0; k4 < 128; ++k4) { float4 a = a14[k4]; FMA16(a, w41, 4*k4,        A0,A1,A2,A3); }
      #pragma unroll 2
      for (int k4 = 0; k4 < 128; ++k4) { float4 a = a24[k4]; FMA16(a, w41, 512 + 4*k4,  B0,B1,B2,B3); }
      #pragma unroll 2
      for (int k4 = 0; k4 < 32;  ++k4) { float4 a = ax4[k4]; FMA16(a, w41, 1024 + 4*k4, X0,X1,X2,X3); }
      float r0 = fmaf(sc1, A0, fmaf(sc2, B0, X0));
      float r1 = fmaf(sc1, A1, fmaf(sc2, B1, X1));
      float r2 = fmaf(sc1, A2, fmaf(sc2, B2, X2));
      float r3 = fmaf(sc1, A3, fmaf(sc2, B3, X3));
      *(float4*)&ls_s[lane][4 * nw] = make_float4(r0, r1, r2, r3);

      // z_hat column, K-sliced across waves (exact fp32)
      float za = 0.f, zb = 0.f, zc = 0.f;
      const int k0 = nw * 144, k1 = k0 + 144;
      const int e1 = k1 < 512 ? k1 : 512;
      const int s2 = k0 > 512 ? k0 : 512;
      const int e2 = k1 < 1024 ? k1 : 1024;
      const int s3 = k0 > 1024 ? k0 : 1024;
      for (int k = k0; k < e1; ++k) za = fmaf(a1[k],        wz1[k], za);
      for (int k = s2; k < e2; ++k) zb = fmaf(a2[k - 512],  wz1[k], zb);
      for (int k = s3; k < k1; ++k) zc = fmaf(ax[k - 1024], wz1[k], zc);
      zred[nw][lane] = fmaf(sc1, za, fmaf(sc2, zb, zc));
    }
    __syncthreads();

    if (tid < 64) {   // reduce z1(t), identical in every WG of this mg
      float s = bz1;
      #pragma unroll
      for (int w = 0; w < 8; ++w) s += zred[w][tid];
      z1n[tid] = fminf(fmaxf((s + 1.f) * 0.5f, 0.f), 1.f);
    }
    {
      // epilogue layer 1 (zb == 1):  c' = z*ig + (1-z)*(f*c + ig);  h' = o*tanh(c')
      float4 sv = *(const float4*)&ls_s[eb][4 * eu];
      float4 bb = *(const float4*)&bp1[c0 + 4 * eu];
      float f = sigmoidf_(sv.x + bb.x);
      float i = sigmoidf_(sv.y + bb.y);
      float o = sigmoidf_(sv.z + bb.z);
      float g = tanhf(sv.w + bb.w);
      float z = z1s[eb];
      float c = c1s[eb][eu];
      float ig = i * g;
      float cn = z * ig + (1.f - z) * fmaf(f, c, ig);
      float hn = o * tanhf(cn);
      c1s[eb][eu] = cn;
      h1wr[(b0 + eb) * HH + j0 + eu] = hn;
    }
    grid.sync();

    // ================= PHASE B (layer 2) =================
    if (tid < 64) z2s[tid] = z2n[tid];   // z2(t-1) becomes current
    __syncthreads();

    {
      const float* a1 = h2rd + row * HH;   // old h2
      const float* a2 = h1wr + row * HH;   // new h1
      const float sc1 = 1.f - z2s[lane];
      const float sc2 = z1n[lane];         // zb = z1(t)
      const float4* a14 = (const float4*)a1;
      const float4* a24 = (const float4*)a2;
      float A0=0,A1=0,A2=0,A3=0, B0=0,B1=0,B2=0,B3=0;
      #pragma unroll 2
      for (int k4 = 0; k4 < 128; ++k4) { float4 a = a14[k4]; FMA16(a, w42, 4*k4,       A0,A1,A2,A3); }
      #pragma unroll 2
      for (int k4 = 0; k4 < 128; ++k4) { float4 a = a24[k4]; FMA16(a, w42, 512 + 4*k4, B0,B1,B2,B3); }
      float r0 = fmaf(sc1, A0, sc2 * B0);
      float r1 = fmaf(sc1, A1, sc2 * B1);
      float r2 = fmaf(sc1, A2, sc2 * B2);
      float r3 = fmaf(sc1, A3, sc2 * B3);
      *(float4*)&ls_s[lane][4 * nw] = make_float4(r0, r1, r2, r3);

      float za = 0.f, zb = 0.f;
      const int k0 = nw * 128, k1 = k0 + 128;
      const int e1 = k1 < 512 ? k1 : 512;
      const int s2 = k0 > 512 ? k0 : 512;
      for (int k = k0; k < e1; ++k) za = fmaf(a1[k],       wz2[k], za);
      for (int k = s2; k < k1; ++k) zb = fmaf(a2[k - 512], wz2[k], zb);
      zred[nw][lane] = fmaf(sc1, za, sc2 * zb);
    }
    __syncthreads();

    if (tid < 64) {
      float s = bz2;
      #pragma unroll
      for (int w = 0; w < 8; ++w) s += zred[w][tid];
      z2n[tid] = fminf(fmaxf((s + 1.f) * 0.5f, 0.f), 1.f);
    }
    {
      // epilogue layer 2 (full HM-LSTM update with z = z2(t-1), zb = z1(t))
      float4 sv = *(const float4*)&ls_s[eb][4 * eu];
      float4 bb = *(const float4*)&bp2[c0 + 4 * eu];
      float f = sigmoidf_(sv.x + bb.x);
      float i = sigmoidf_(sv.y + bb.y);
      float o = sigmoidf_(sv.z + bb.z);
      float g = tanhf(sv.w + bb.w);
      float z  = z2s[eb];
      float zbv = z1n[eb];
      float c = c2s[eb][eu];
      float ig = i * g;
      float cn = z * ig + (1.f - z) * (1.f - zbv) * c + (1.f - z) * zbv * fmaf(f, c, ig);
      float tc = tanhf(cn);
      float ho = h2loc[eb][eu];
      float ot = o * tc;
      float hn = z * ot + (1.f - z) * (1.f - zbv) * ho + (1.f - z) * zbv * ot;
      c2s[eb][eu] = cn;
      h2loc[eb][eu] = hn;
      h2wr[(b0 + eb) * HH + j0 + eu] = hn;
    }
    grid.sync();
    p ^= 1;
  }

  // final output y(T-1) = h2(T-1) * z2(T-1)
  y[((size_t)(b0 + eb) * TT + (TT - 1)) * HH + j0 + eu] = h2loc[eb][eu] * z2n[eb];
}

extern "C" void kernel_launch(void* const* d_in, const int* in_sizes, int n_in,
                              void* d_out, int out_size, void* d_ws, size_t ws_size,
                              hipStream_t stream) {
  const float* x     = (const float*)d_in[0];
  const float* U11_1 = (const float*)d_in[1];
  const float* U21_1 = (const float*)d_in[2];
  const float* W01_1 = (const float*)d_in[3];
  const float* b1    = (const float*)d_in[4];
  const float* U11_2 = (const float*)d_in[5];
  const float* W01_2 = (const float*)d_in[6];
  const float* b2    = (const float*)d_in[7];
  float* ws = (float*)d_ws;
  float* y  = (float*)d_out;

  (void)in_sizes; (void)n_in; (void)out_size; (void)ws_size;

  // Pack weights (gate-interleaved columns), z-rows, biases; zero h state buffers.
  unsigned nblk = (N_TOT + 255u) / 256u;
  hipLaunchKernelGGL(pack_kernel, dim3(nblk), dim3(256), 0, stream,
                     U11_1, U21_1, W01_1, b1, U11_2, W01_2, b2, ws);

  const float* xq = x;
  float* wsq = ws;
  float* yq = y;
  void* kargs[] = { (void*)&xq, (void*)&wsq, (void*)&yq };
  hipLaunchCooperativeKernel((void*)hmlstm_kernel, dim3(256), dim3(512), kargs, 0, stream);
}

// Round 2
// 67408.264 us; speedup vs baseline: 3.3538x; 3.3538x over previous
//
#include <hip/hip_runtime.h>
#include <hip/hip_cooperative_groups.h>

namespace cg = cooperative_groups;

#define TT 512
#define BB 256
#define DD 128
#define HH 512
#define KA 1152   // 512 (h1*(1-z1)) + 512 (h2*z1) + 128 (x)
#define KB 1024   // 512 (h2*(1-z2)) + 512 (h1new*z1)
#define NKA 36    // KA/32
#define NKB 32    // KB/32

// ---- ws byte-offset layout ----
#define OFF_WPA 0ull
#define SZ_WPA  (128ull*NKA*2ull*512ull*2ull)   // 9,437,184 B  [colblk][kb][split][lane][8] bf16
#define OFF_WPB (OFF_WPA + SZ_WPA)
#define SZ_WPB  (128ull*NKB*2ull*512ull*2ull)   // 8,388,608 B
#define OFF_WZ1 (OFF_WPB + SZ_WPB)              // f32[1152]
#define OFF_WZ2 (OFF_WZ1 + (unsigned long long)KA*4ull)   // f32[1024]
#define OFF_BP1 (OFF_WZ2 + (unsigned long long)KB*4ull)   // f32[2048] permuted bias l1
#define OFF_BP2 (OFF_BP1 + 2048ull*4ull)                  // f32[2048]
#define OFF_BZ  (OFF_BP2 + 2048ull*4ull)                  // bz1, bz2
#define OFF_ACTA (OFF_BZ + 256ull)              // u16 [buf][split][row][KA], 2 bufs
#define SZ_ACTA (2ull*2ull*BB*KA*2ull)          // 2,359,296 B
#define OFF_ACTB (OFF_ACTA + SZ_ACTA)           // u16 [buf][split][row][KB]
#define SZ_ACTB (2ull*2ull*BB*KB*2ull)          // 2,097,152 B

typedef __bf16 bf16x8 __attribute__((ext_vector_type(8)));
typedef float  f32x4  __attribute__((ext_vector_type(4)));

__device__ __forceinline__ unsigned short bf_bits(__bf16 h) {
  union { __bf16 b; unsigned short u; } cv; cv.b = h; return cv.u;
}
__device__ __forceinline__ void split_store(unsigned short* hi, unsigned short* lo, float v) {
  __bf16 h = (__bf16)v;
  __bf16 l = (__bf16)(v - (float)h);
  *hi = bf_bits(h);
  *lo = bf_bits(l);
}
__device__ __forceinline__ float sigmoidf_(float v) { return 1.f / (1.f + __expf(-v)); }

// ---------------- pack kernels ----------------
// Weights in B-fragment order: element (colblk, kb, s, lane, e) =
//   W_split_s[col = colblk*16 + (lane&15)][k = kb*32 + (lane>>4)*8 + e]
// permuted col c -> source row n = (c&3)*512 + (c>>2)  (gate-interleaved units)
__global__ void pack_w(const float* __restrict__ U11_1, const float* __restrict__ U21_1,
                       const float* __restrict__ W01_1, const float* __restrict__ U11_2,
                       const float* __restrict__ W01_2, unsigned short* __restrict__ wp) {
  unsigned i = blockIdx.x * 256u + threadIdx.x;
  const unsigned NWA = 128u * NKA * 2u * 512u;   // 4,718,592 u16
  const unsigned NWB = 128u * NKB * 2u * 512u;   // 4,194,304 u16
  if (i >= NWA + NWB) return;
  float w; unsigned s;
  if (i < NWA) {
    unsigned lane = (i >> 3) & 63u, e = i & 7u; s = (i >> 9) & 1u;
    unsigned blk = i >> 10, kb = blk % NKA, colblk = blk / NKA;
    unsigned c = colblk * 16u + (lane & 15u);
    unsigned n = (c & 3u) * 512u + (c >> 2);
    unsigned k = kb * 32u + (lane >> 4) * 8u + e;
    w = (k < 512u)  ? U11_1[n * 512u + k]
      : (k < 1024u) ? U21_1[n * 512u + (k - 512u)]
                    : W01_1[n * 128u + (k - 1024u)];
  } else {
    unsigned j = i - NWA;
    unsigned lane = (j >> 3) & 63u, e = j & 7u; s = (j >> 9) & 1u;
    unsigned blk = j >> 10, kb = blk % NKB, colblk = blk / NKB;
    unsigned c = colblk * 16u + (lane & 15u);
    unsigned n = (c & 3u) * 512u + (c >> 2);
    unsigned k = kb * 32u + (lane >> 4) * 8u + e;
    w = (k < 512u) ? U11_2[n * 512u + k] : W01_2[n * 512u + (k - 512u)];
  }
  __bf16 hi = (__bf16)w;
  __bf16 v = s ? (__bf16)(w - (float)hi) : hi;
  wp[i] = bf_bits(v);
}

// f32 block: wz1[1152], wz2[1024], bp1[2048], bp2[2048], bz1, bz2
__global__ void pack_misc(const float* __restrict__ U11_1, const float* __restrict__ U21_1,
                          const float* __restrict__ W01_1, const float* __restrict__ b1,
                          const float* __restrict__ U11_2, const float* __restrict__ W01_2,
                          const float* __restrict__ b2, float* __restrict__ wf) {
  unsigned i = blockIdx.x * 256u + threadIdx.x;
  if (i >= 6274u) return;
  float v;
  if (i < 1152u) {
    unsigned k = i;
    v = (k < 512u)  ? U11_1[2048u*512u + k]
      : (k < 1024u) ? U21_1[2048u*512u + (k-512u)]
                    : W01_1[2048u*128u + (k-1024u)];
  } else if (i < 2176u) {
    unsigned k = i - 1152u;
    v = (k < 512u) ? U11_2[2048u*512u + k] : W01_2[2048u*512u + (k-512u)];
  } else if (i < 4224u) {
    unsigned c = i - 2176u;
    v = b1[(c & 3u)*512u + (c >> 2)];
  } else if (i < 6272u) {
    unsigned c = i - 4224u;
    v = b2[(c & 3u)*512u + (c >> 2)];
  } else if (i == 6272u) v = b1[2048];
  else                   v = b2[2048];
  wf[i] = v;
}

// acts: zero everything; buf0 of actA gets split(x[:,0,:]) at k>=1024
__global__ void pack_act(const float* __restrict__ x, unsigned short* __restrict__ acta,
                         unsigned short* __restrict__ actb) {
  unsigned i = blockIdx.x * 256u + threadIdx.x;
  const unsigned NA = 2u*2u*BB*KA;
  const unsigned NB = 2u*2u*BB*KB;
  if (i < NA) {
    unsigned k = i % KA;
    unsigned r = (i / KA) % BB;
    unsigned s = (i / (KA*BB)) & 1u;
    unsigned buf = i / (KA*BB*2u);
    unsigned short out = 0;
    if (buf == 0u && k >= 1024u) {
      float xv = x[(size_t)r * (TT*DD) + (k - 1024u)];
      __bf16 hi = (__bf16)xv;
      __bf16 o = s ? (__bf16)(xv - (float)hi) : hi;
      out = bf_bits(o);
    }
    acta[i] = out;
  } else if (i < NA + NB) {
    actb[i - NA] = 0;
  }
}

// ---------------- main persistent kernel ----------------
// 256 WGs x 512 threads. bid swizzle: XCD x owns nt in [8x, 8x+8) for all 4 mgs
// -> per-XCD weight footprint 2.2 MB (L2-resident across steps).
// Wave nw: mf=nw>>1 (m-frag 0..3), nf=nw&1 (n-frag 0..1); one 16x16 out frag,
// 3 MFMA chains per kblock (hi*hi, hi*lo, lo*hi).
__global__ __launch_bounds__(512, 2) void hmlstm_kernel(const float* __restrict__ x,
                                                        char* __restrict__ wsb,
                                                        float* __restrict__ y) {
  cg::grid_group grid = cg::this_grid();
  const int tid  = threadIdx.x;
  const int lane = tid & 63;
  const int nw   = __builtin_amdgcn_readfirstlane(tid >> 6);
  const int bid  = blockIdx.x;
  const int nt   = (bid & 7) * 8 + ((bid >> 3) & 7);   // 0..63
  const int mg   = bid >> 6;                            // 0..3
  const int nf   = nw & 1;
  const int b0 = mg * 64;
  const int j0 = nt * 8;
  const int c0 = nt * 32;
  const int colblk = nt * 2 + nf;

  const unsigned short* wpA = (const unsigned short*)(wsb + OFF_WPA);
  const unsigned short* wpB = (const unsigned short*)(wsb + OFF_WPB);
  const float* wz1 = (const float*)(wsb + OFF_WZ1);
  const float* wz2 = (const float*)(wsb + OFF_WZ2);
  const float* bp1 = (const float*)(wsb + OFF_BP1);
  const float* bp2 = (const float*)(wsb + OFF_BP2);
  const float bz1 = ((const float*)(wsb + OFF_BZ))[0];
  const float bz2 = ((const float*)(wsb + OFF_BZ))[1];
  unsigned short* actA = (unsigned short*)(wsb + OFF_ACTA);
  unsigned short* actB = (unsigned short*)(wsb + OFF_ACTB);

  __shared__ float ls_s[64][36];
  __shared__ float zred[8][64];
  __shared__ float c1s[64][8], c2s[64][8], h2loc[64][8];
  __shared__ float z1s[64], z2s[64], z1n[64], z2n[64];

  { int b = tid >> 3, u = tid & 7;
    c1s[b][u] = 0.f; c2s[b][u] = 0.f; h2loc[b][u] = 0.f; }
  if (tid < 64) { z1s[tid] = 0.f; z2s[tid] = 0.f; z1n[tid] = 0.f; z2n[tid] = 0.f; }
  __syncthreads();

  const int arow = (nw >> 1) * 16 + (lane & 15);  // local row 0..63
  const int kgrp = (lane >> 4) * 8;
  const int eb = tid >> 3, eu = tid & 7;          // epilogue (row, unit)
  const int erow = b0 + eb;

  int p = 0;
  for (int t = 0; t < TT; ++t) {
    // ================= PHASE A (layer 1) =================
    if (tid < 64) z1s[tid] = z1n[tid];
    __syncthreads();
    {
      const unsigned short* ah = actA + (size_t)(p*2 + 0) * (BB*KA);
      const unsigned short* al = actA + (size_t)(p*2 + 1) * (BB*KA);
      const size_t rbase = (size_t)(b0 + arow) * KA + kgrp;
      const unsigned short* wb = wpA + (size_t)colblk * (NKA*1024u) + lane*8;
      f32x4 acc0 = {0.f,0.f,0.f,0.f}, acc1 = {0.f,0.f,0.f,0.f}, acc2 = {0.f,0.f,0.f,0.f};
      #pragma unroll 4
      for (int kb = 0; kb < NKA; ++kb) {
        bf16x8 ahv = *(const bf16x8*)(ah + rbase + kb*32);
        bf16x8 alv = *(const bf16x8*)(al + rbase + kb*32);
        bf16x8 bhv = *(const bf16x8*)(wb + kb*1024);
        bf16x8 blv = *(const bf16x8*)(wb + kb*1024 + 512);
        acc0 = __builtin_amdgcn_mfma_f32_16x16x32_bf16(ahv, bhv, acc0, 0, 0, 0);
        acc1 = __builtin_amdgcn_mfma_f32_16x16x32_bf16(ahv, blv, acc1, 0, 0, 0);
        acc2 = __builtin_amdgcn_mfma_f32_16x16x32_bf16(alv, bhv, acc2, 0, 0, 0);
      }
      f32x4 accs = acc0 + acc1;
      accs = accs + acc2;
      {
        const int r0 = (nw >> 1) * 16 + (lane >> 4) * 4;
        const int cc = nf * 16 + (lane & 15);
        ls_s[r0 + 0][cc] = accs[0];
        ls_s[r0 + 1][cc] = accs[1];
        ls_s[r0 + 2][cc] = accs[2];
        ls_s[r0 + 3][cc] = accs[3];
      }
      // z_hat (exact-order, per-WG redundant -> deterministic across WGs)
      const unsigned short* ahz = ah + (size_t)(b0 + lane) * KA;
      const unsigned short* alz = al + (size_t)(b0 + lane) * KA;
      float za0 = 0.f, za1 = 0.f;
      const int k0 = nw * 144;
      #pragma unroll 2
      for (int i8 = 0; i8 < 18; ++i8) {
        int k = k0 + i8 * 8;
        bf16x8 hv = *(const bf16x8*)(ahz + k);
        bf16x8 lv = *(const bf16x8*)(alz + k);
        #pragma unroll
        for (int j = 0; j < 4; ++j)
          za0 = fmaf((float)hv[j] + (float)lv[j], wz1[k + j], za0);
        #pragma unroll
        for (int j = 4; j < 8; ++j)
          za1 = fmaf((float)hv[j] + (float)lv[j], wz1[k + j], za1);
      }
      zred[nw][lane] = za0 + za1;
    }
    __syncthreads();
    if (tid < 64) {
      float s = bz1;
      #pragma unroll
      for (int w = 0; w < 8; ++w) s += zred[w][tid];
      z1n[tid] = fminf(fmaxf((s + 1.f) * 0.5f, 0.f), 1.f);
    }
    __syncthreads();
    {
      // epilogue layer 1 (zb==1): c' = z*ig + (1-z)*(f*c + ig); h' = o*tanh(c')
      float4 sv = *(const float4*)&ls_s[eb][4 * eu];
      float4 bb = *(const float4*)&bp1[c0 + 4 * eu];
      float f = sigmoidf_(sv.x + bb.x);
      float i = sigmoidf_(sv.y + bb.y);
      float o = sigmoidf_(sv.z + bb.z);
      float g = tanhf(sv.w + bb.w);
      float z = z1s[eb];
      float c = c1s[eb][eu];
      float ig = i * g;
      float cn = z * ig + (1.f - z) * fmaf(f, c, ig);
      float hn = o * tanhf(cn);
      c1s[eb][eu] = cn;
      float zn = z1n[eb];
      // actB[p] k in [512,1024): z1(t)*h1(t)   (read by phase B this step)
      size_t ob = ((size_t)(p*2 + 0) * BB + erow) * KB + 512 + j0 + eu;
      split_store(&actB[ob], &actB[ob + (size_t)BB*KB], zn * hn);
      // actA[p^1] k in [0,512): (1-z1(t))*h1(t)   (read by phase A next step)
      size_t oa = ((size_t)((p^1)*2 + 0) * BB + erow) * KA + j0 + eu;
      split_store(&actA[oa], &actA[oa + (size_t)BB*KA], (1.f - zn) * hn);
    }
    grid.sync();

    // ================= PHASE B (layer 2) =================
    if (tid < 64) z2s[tid] = z2n[tid];
    __syncthreads();
    {
      const unsigned short* ah = actB + (size_t)(p*2 + 0) * (BB*KB);
      const unsigned short* al = actB + (size_t)(p*2 + 1) * (BB*KB);
      const size_t rbase = (size_t)(b0 + arow) * KB + kgrp;
      const unsigned short* wb = wpB + (size_t)colblk * (NKB*1024u) + lane*8;
      f32x4 acc0 = {0.f,0.f,0.f,0.f}, acc1 = {0.f,0.f,0.f,0.f}, acc2 = {0.f,0.f,0.f,0.f};
      #pragma unroll 4
      for (int kb = 0; kb < NKB; ++kb) {
        bf16x8 ahv = *(const bf16x8*)(ah + rbase + kb*32);
        bf16x8 alv = *(const bf16x8*)(al + rbase + kb*32);
        bf16x8 bhv = *(const bf16x8*)(wb + kb*1024);
        bf16x8 blv = *(const bf16x8*)(wb + kb*1024 + 512);
        acc0 = __builtin_amdgcn_mfma_f32_16x16x32_bf16(ahv, bhv, acc0, 0, 0, 0);
        acc1 = __builtin_amdgcn_mfma_f32_16x16x32_bf16(ahv, blv, acc1, 0, 0, 0);
        acc2 = __builtin_amdgcn_mfma_f32_16x16x32_bf16(alv, bhv, acc2, 0, 0, 0);
      }
      f32x4 accs = acc0 + acc1;
      accs = accs + acc2;
      {
        const int r0 = (nw >> 1) * 16 + (lane >> 4) * 4;
        const int cc = nf * 16 + (lane & 15);
        ls_s[r0 + 0][cc] = accs[0];
        ls_s[r0 + 1][cc] = accs[1];
        ls_s[r0 + 2][cc] = accs[2];
        ls_s[r0 + 3][cc] = accs[3];
      }
      const unsigned short* ahz = ah + (size_t)(b0 + lane) * KB;
      const unsigned short* alz = al + (size_t)(b0 + lane) * KB;
      float za0 = 0.f, za1 = 0.f;
      const int k0 = nw * 128;
      #pragma unroll 2
      for (int i8 = 0; i8 < 16; ++i8) {
        int k = k0 + i8 * 8;
        bf16x8 hv = *(const bf16x8*)(ahz + k);
        bf16x8 lv = *(const bf16x8*)(alz + k);
        #pragma unroll
        for (int j = 0; j < 4; ++j)
          za0 = fmaf((float)hv[j] + (float)lv[j], wz2[k + j], za0);
        #pragma unroll
        for (int j = 4; j < 8; ++j)
          za1 = fmaf((float)hv[j] + (float)lv[j], wz2[k + j], za1);
      }
      zred[nw][lane] = za0 + za1;
    }
    __syncthreads();
    if (tid < 64) {
      float s = bz2;
      #pragma unroll
      for (int w = 0; w < 8; ++w) s += zred[w][tid];
      z2n[tid] = fminf(fmaxf((s + 1.f) * 0.5f, 0.f), 1.f);
    }
    __syncthreads();
    {
      // epilogue layer 2: z = z2(t-1), zb = z1(t)
      float4 sv = *(const float4*)&ls_s[eb][4 * eu];
      float4 bb = *(const float4*)&bp2[c0 + 4 * eu];
      float f = sigmoidf_(sv.x + bb.x);
      float i = sigmoidf_(sv.y + bb.y);
      float o = sigmoidf_(sv.z + bb.z);
      float g = tanhf(sv.w + bb.w);
      float z   = z2s[eb];
      float zbv = z1n[eb];
      float c = c2s[eb][eu];
      float ig = i * g;
      float cn = z * ig + (1.f - z) * (1.f - zbv) * c + (1.f - z) * zbv * fmaf(f, c, ig);
      float tc = tanhf(cn);
      float ho = h2loc[eb][eu];
      float ot = o * tc;
      float hn = z * ot + (1.f - z) * (1.f - zbv) * ho + (1.f - z) * zbv * ot;
      c2s[eb][eu] = cn;
      h2loc[eb][eu] = hn;
      float z2new = z2n[eb];
      y[((size_t)erow * TT + t) * HH + j0 + eu] = hn * z2new;
      // actB[p^1] k in [0,512): (1-z2(t))*h2(t)
      size_t ob = ((size_t)((p^1)*2 + 0) * BB + erow) * KB + j0 + eu;
      split_store(&actB[ob], &actB[ob + (size_t)BB*KB], (1.f - z2new) * hn);
      // actA[p^1] k in [512,1024): z1(t)*h2(t)
      size_t oa = ((size_t)((p^1)*2 + 0) * BB + erow) * KA + 512 + j0 + eu;
      split_store(&actA[oa], &actA[oa + (size_t)BB*KA], z1n[eb] * hn);
      // x split for t+1 (2 k per WG per row)
      if (eu < 2 && t + 1 < TT) {
        int k = nt * 2 + eu;
        float xv = x[((size_t)erow * TT + (t + 1)) * DD + k];
        size_t ox = ((size_t)((p^1)*2 + 0) * BB + erow) * KA + 1024 + k;
        split_store(&actA[ox], &actA[ox + (size_t)BB*KA], xv);
      }
    }
    grid.sync();
    p ^= 1;
  }
}

extern "C" void kernel_launch(void* const* d_in, const int* in_sizes, int n_in,
                              void* d_out, int out_size, void* d_ws, size_t ws_size,
                              hipStream_t stream) {
  const float* x     = (const float*)d_in[0];
  const float* U11_1 = (const float*)d_in[1];
  const float* U21_1 = (const float*)d_in[2];
  const float* W01_1 = (const float*)d_in[3];
  const float* b1    = (const float*)d_in[4];
  const float* U11_2 = (const float*)d_in[5];
  const float* W01_2 = (const float*)d_in[6];
  const float* b2    = (const float*)d_in[7];
  char*  wsb = (char*)d_ws;
  float* y   = (float*)d_out;
  (void)in_sizes; (void)n_in; (void)out_size; (void)ws_size;

  unsigned short* wp   = (unsigned short*)(wsb + OFF_WPA);
  unsigned short* acta = (unsigned short*)(wsb + OFF_ACTA);
  unsigned short* actb = (unsigned short*)(wsb + OFF_ACTB);
  float* wf = (float*)(wsb + OFF_WZ1);

  const unsigned NW = 128u*NKA*2u*512u + 128u*NKB*2u*512u;   // 8,912,896
  hipLaunchKernelGGL(pack_w, dim3((NW + 255u) / 256u), dim3(256), 0, stream,
                     U11_1, U21_1, W01_1, U11_2, W01_2, wp);
  hipLaunchKernelGGL(pack_misc, dim3(25), dim3(256), 0, stream,
                     U11_1, U21_1, W01_1, b1, U11_2, W01_2, b2, wf);
  const unsigned NACT = 2u*2u*BB*KA + 2u*2u*BB*KB;            // 2,228,224
  hipLaunchKernelGGL(pack_act, dim3((NACT + 255u) / 256u), dim3(256), 0, stream,
                     x, acta, actb);

  const float* xq = x;
  char* wsq = wsb;
  float* yq = y;
  void* kargs[] = { (void*)&xq, (void*)&wsq, (void*)&yq };
  hipLaunchCooperativeKernel((void*)hmlstm_kernel, dim3(256), dim3(512), kargs, 0, stream);
}

// Round 3
// 66736.664 us; speedup vs baseline: 3.3875x; 1.0101x over previous
//
#include <hip/hip_runtime.h>
#include <hip/hip_cooperative_groups.h>

namespace cg = cooperative_groups;

#define TT 512
#define BB 256
#define DD 128
#define HH 512
#define KA 1152   // 512 (h1*(1-z1)) + 512 (h2*z1) + 128 (x)
#define KB 1024   // 512 (h2*(1-z2)) + 512 (h1new*z1)
#define NKA 36    // KA/32
#define NKB 32    // KB/32
#define NCHA 9    // KA/128 chunks
#define NCHB 8    // KB/128 chunks

// ---- ws byte-offset layout ----
#define OFF_WPA  0ull
#define SZ_WPA   (128ull*NKA*2ull*512ull*2ull)     // [colblk][kb][split][lane][8] bf16
#define OFF_WPB  (OFF_WPA + SZ_WPA)
#define SZ_WPB   (128ull*NKB*2ull*512ull*2ull)
#define OFF_WZFA (OFF_WPB + SZ_WPB)                // [kb][lane][8] u16 (col0=hi,col1=lo)
#define SZ_WZFA  (36ull*512ull*2ull)
#define OFF_WZFB (OFF_WZFA + SZ_WZFA)
#define SZ_WZFB  (32ull*512ull*2ull)
#define OFF_BP1  (OFF_WZFB + SZ_WZFB)              // f32[2048] permuted bias l1
#define OFF_BP2  (OFF_BP1 + 8192ull)
#define OFF_BZ   (OFF_BP2 + 8192ull)               // bz1, bz2
#define OFF_ACTA (OFF_BZ + 256ull)                 // u16 [p][split][kbc 9][row 256][16 gran][8]
#define SZ_ACTA  (2ull*2ull*NCHA*256ull*128ull*2ull)
#define OFF_ACTB (OFF_ACTA + SZ_ACTA)              // u16 [p][split][kbc 8][row 256][16 gran][8]
#define SZ_ACTB  (2ull*2ull*NCHB*256ull*128ull*2ull)

#define SPL_A (NCHA*32768)   // u16 offset between split planes (p term), actA
#define SPL_B (NCHB*32768)

typedef __bf16 bf16x8 __attribute__((ext_vector_type(8)));
typedef float  f32x4  __attribute__((ext_vector_type(4)));
typedef unsigned short u16;

__device__ __forceinline__ u16 bf_bits(__bf16 h) {
  union { __bf16 b; u16 u; } cv; cv.b = h; return cv.u;
}
__device__ __forceinline__ void split_store(u16* hi, u16* lo, float v) {
  __bf16 h = (__bf16)v;
  __bf16 l = (__bf16)(v - (float)h);
  *hi = bf_bits(h);
  *lo = bf_bits(l);
}
__device__ __forceinline__ float sigmoidf_(float v) { return 1.f / (1.f + __expf(-v)); }

// act element (p, split, row, k) -> u16 index; swizzled granule layout:
// granule-in-plane = row*16 + (gk ^ (row&7)), gk = (k>>3)&15 within 128-k chunk
__device__ __forceinline__ size_t act_idx(int nch, int p, int split, int row, int k) {
  int kbc = k >> 7;
  int gsw = ((k >> 3) & 15) ^ (row & 7);
  return ((((size_t)((p*2 + split)*nch + kbc) * 256 + row) << 4) + gsw) * 8 + (k & 7);
}

__device__ __forceinline__ void gload_lds16(const void* g, void* l) {
  __builtin_amdgcn_global_load_lds((const __attribute__((address_space(1))) unsigned int*)g,
                                   (__attribute__((address_space(3))) unsigned int*)l, 16, 0, 0);
}

// stage one 32KB chunk (64 rows x 128 k x 2 splits) into LDS buf (linear image)
__device__ __forceinline__ void stage_chunk(const u16* __restrict__ act, int nch, int pp,
                                            int kbc, int b0, int nw, int lane, char* buf) {
  #pragma unroll
  for (int i = 0; i < 4; ++i) {
    const int Lb = i*512 + nw*64;          // wave-uniform LDS granule base
    const int Ll = Lb + lane;
    const int split = Ll >> 10;
    const int rl = (Ll >> 4) & 63;
    const int g = Ll & 15;
    const u16* gp = act + (((size_t)((pp*2 + split)*nch + kbc)*256 + (b0 + rl))*16 + g)*8;
    gload_lds16(gp, buf + (size_t)Lb*16);
  }
}

__device__ __forceinline__ void loadw(const u16* wb, int c, bf16x8* W) {
  #pragma unroll
  for (int q = 0; q < 4; ++q) {
    W[2*q]   = *(const bf16x8*)(wb + (size_t)(c*4+q)*1024);
    W[2*q+1] = *(const bf16x8*)(wb + (size_t)(c*4+q)*1024 + 512);
  }
}
__device__ __forceinline__ void loadz(const u16* wzl, int c, bf16x8* Z) {
  #pragma unroll
  for (int q = 0; q < 4; ++q) Z[q] = *(const bf16x8*)(wzl + (size_t)(c*4+q)*512);
}

// ---------------- pack kernels ----------------
__global__ void pack_w(const float* __restrict__ U11_1, const float* __restrict__ U21_1,
                       const float* __restrict__ W01_1, const float* __restrict__ U11_2,
                       const float* __restrict__ W01_2, u16* __restrict__ wp) {
  unsigned i = blockIdx.x * 256u + threadIdx.x;
  const unsigned NWA = 128u * NKA * 2u * 512u;
  const unsigned NWB = 128u * NKB * 2u * 512u;
  if (i >= NWA + NWB) return;
  float w; unsigned s;
  if (i < NWA) {
    unsigned lane = (i >> 3) & 63u, e = i & 7u; s = (i >> 9) & 1u;
    unsigned blk = i >> 10, kb = blk % NKA, colblk = blk / NKA;
    unsigned c = colblk * 16u + (lane & 15u);
    unsigned n = (c & 3u) * 512u + (c >> 2);
    unsigned k = kb * 32u + (lane >> 4) * 8u + e;
    w = (k < 512u)  ? U11_1[n * 512u + k]
      : (k < 1024u) ? U21_1[n * 512u + (k - 512u)]
                    : W01_1[n * 128u + (k - 1024u)];
  } else {
    unsigned j = i - NWA;
    unsigned lane = (j >> 3) & 63u, e = j & 7u; s = (j >> 9) & 1u;
    unsigned blk = j >> 10, kb = blk % NKB, colblk = blk / NKB;
    unsigned c = colblk * 16u + (lane & 15u);
    unsigned n = (c & 3u) * 512u + (c >> 2);
    unsigned k = kb * 32u + (lane >> 4) * 8u + e;
    w = (k < 512u) ? U11_2[n * 512u + k] : W01_2[n * 512u + (k - 512u)];
  }
  __bf16 hi = (__bf16)w;
  __bf16 v = s ? (__bf16)(w - (float)hi) : hi;
  wp[i] = bf_bits(v);
}

__global__ void pack_wz(const float* __restrict__ U11_1, const float* __restrict__ U21_1,
                        const float* __restrict__ W01_1, const float* __restrict__ U11_2,
                        const float* __restrict__ W01_2,
                        u16* __restrict__ wzfa, u16* __restrict__ wzfb) {
  unsigned i = blockIdx.x * 256u + threadIdx.x;
  const unsigned NZA = 36u * 512u, NZB = 32u * 512u;
  if (i >= NZA + NZB) return;
  const bool isA = i < NZA;
  unsigned j = isA ? i : i - NZA;
  unsigned e = j & 7u, lane = (j >> 3) & 63u, kb = j >> 9;
  unsigned col = lane & 15u;
  unsigned k = kb * 32u + (lane >> 4) * 8u + e;
  float wz;
  if (isA) {
    wz = (k < 512u)  ? U11_1[2048u*512u + k]
       : (k < 1024u) ? U21_1[2048u*512u + (k-512u)]
                     : W01_1[2048u*128u + (k-1024u)];
  } else {
    wz = (k < 512u) ? U11_2[2048u*512u + k] : W01_2[2048u*512u + (k-512u)];
  }
  u16 out = 0;
  if (col == 0u) out = bf_bits((__bf16)wz);
  else if (col == 1u) { __bf16 h = (__bf16)wz; out = bf_bits((__bf16)(wz - (float)h)); }
  (isA ? wzfa : wzfb)[j] = out;
}

__global__ void pack_bias(const float* __restrict__ b1, const float* __restrict__ b2,
                          float* __restrict__ bp1, float* __restrict__ bp2,
                          float* __restrict__ bz) {
  unsigned i = blockIdx.x * 256u + threadIdx.x;
  if (i < 2048u) bp1[i] = b1[(i & 3u)*512u + (i >> 2)];
  else if (i < 4096u) { unsigned c = i - 2048u; bp2[c] = b2[(c & 3u)*512u + (c >> 2)]; }
  else if (i == 4096u) bz[0] = b1[2048];
  else if (i == 4097u) bz[1] = b2[2048];
}

// zero act arrays; actA p=0, k>=1024 gets split(x[:, t=0, :]) in swizzled layout
__global__ void pack_act(const float* __restrict__ x, u16* __restrict__ acta,
                         u16* __restrict__ actb) {
  unsigned i = blockIdx.x * 256u + threadIdx.x;
  const unsigned NAu = 2u*2u*NCHA*256u*128u;
  const unsigned NBu = 2u*2u*NCHB*256u*128u;
  if (i < NAu) {
    unsigned e = i & 7u, gsw = (i >> 3) & 15u, row = (i >> 7) & 255u;
    unsigned rest = i >> 15;
    unsigned kbc = rest % NCHA, ps = rest / NCHA;
    unsigned p = ps >> 1, s = ps & 1u;
    unsigned gk = gsw ^ (row & 7u);
    unsigned k = kbc*128u + gk*8u + e;
    u16 out = 0;
    if (p == 0u && k >= 1024u) {
      float xv = x[(size_t)row * (TT*DD) + (k - 1024u)];
      __bf16 hi = (__bf16)xv;
      __bf16 o = s ? (__bf16)(xv - (float)hi) : hi;
      out = bf_bits(o);
    }
    acta[i] = out;
  } else if (i < NAu + NBu) {
    actb[i - NAu] = 0;
  }
}

// ---------------- main persistent kernel ----------------
// 256 WGs x 512 threads; WG = 64 rows (mg) x 32 cols (nt). XCD x owns nt in
// [8x,8x+8) for all 4 mgs -> per-XCD weight footprint 2.2 MB.
// 8 waves = 4 mf x 2 nf. Per chunk (4 kbs): stage(c+1) async -> ds_read+MFMA(c)
// -> __syncthreads. z_hat = extra MFMA B-columns (wz_hi, wz_lo) on nf==0 waves.
__global__ __launch_bounds__(512, 2) void hmlstm_kernel(const float* __restrict__ x,
                                                        char* __restrict__ wsb,
                                                        float* __restrict__ y) {
  cg::grid_group grid = cg::this_grid();
  const int tid  = threadIdx.x;
  const int lane = tid & 63;
  const int nw   = __builtin_amdgcn_readfirstlane(tid >> 6);
  const int bid  = blockIdx.x;
  const int nt   = (bid & 7) * 8 + ((bid >> 3) & 7);   // 0..63
  const int mg   = bid >> 6;                            // 0..3
  const int nf   = nw & 1;
  const int mf   = nw >> 1;
  const int b0 = mg * 64;
  const int j0 = nt * 8;
  const int c0 = nt * 32;
  const int colblk = nt * 2 + nf;

  const u16* wpA  = (const u16*)(wsb + OFF_WPA);
  const u16* wpB  = (const u16*)(wsb + OFF_WPB);
  const u16* wzfA = (const u16*)(wsb + OFF_WZFA);
  const u16* wzfB = (const u16*)(wsb + OFF_WZFB);
  const float* bp1 = (const float*)(wsb + OFF_BP1);
  const float* bp2 = (const float*)(wsb + OFF_BP2);
  const float bz1 = ((const float*)(wsb + OFF_BZ))[0];
  const float bz2 = ((const float*)(wsb + OFF_BZ))[1];
  u16* actA = (u16*)(wsb + OFF_ACTA);
  u16* actB = (u16*)(wsb + OFF_ACTB);

  __shared__ char stg[2][32768] __attribute__((aligned(16)));
  __shared__ float ls_s[64][36];
  __shared__ float zcols[3][64];
  __shared__ float c1s[64][8], c2s[64][8], h2loc[64][8];
  __shared__ float z1s[64], z2s[64], z1n[64], z2n[64];

  { int b = tid >> 3, u = tid & 7;
    c1s[b][u] = 0.f; c2s[b][u] = 0.f; h2loc[b][u] = 0.f; }
  if (tid < 64) { z1s[tid] = 0.f; z2s[tid] = 0.f; z1n[tid] = 0.f; z2n[tid] = 0.f; }
  __syncthreads();

  const int arow = mf * 16 + (lane & 15);   // local row 0..63
  const int kq   = lane >> 4;               // k-subgroup 0..3
  const int eb = tid >> 3, eu = tid & 7;    // epilogue (row, unit)
  const int erow = b0 + eb;

  const u16* wbA   = wpA + (size_t)colblk * (NKA*1024u) + lane*8;
  const u16* wbB   = wpB + (size_t)colblk * (NKB*1024u) + lane*8;
  const u16* wzfAl = wzfA + lane*8;
  const u16* wzfBl = wzfB + lane*8;

  int p = 0;
  for (int t = 0; t < TT; ++t) {
    // ================= PHASE A (layer 1) =================
    if (tid < 64) z1s[tid] = z1n[tid];   // z1(t-1)
    {
      bf16x8 wcur[8], wnxt[8], zwc[4], zwn[4];
      stage_chunk(actA, NCHA, p, 0, b0, nw, lane, stg[0]);
      loadw(wbA, 0, wcur);
      if (nf == 0) loadz(wzfAl, 0, zwc);
      f32x4 acc0 = {0.f,0.f,0.f,0.f}, acc1 = {0.f,0.f,0.f,0.f}, acc2 = {0.f,0.f,0.f,0.f};
      f32x4 az0  = {0.f,0.f,0.f,0.f}, az1  = {0.f,0.f,0.f,0.f};
      __syncthreads();   // stage0 + weights ready; also covers z1s copy
      for (int c = 0; c < NCHA; ++c) {
        char* sb = stg[c & 1];
        if (c + 1 < NCHA) {
          stage_chunk(actA, NCHA, p, c + 1, b0, nw, lane, stg[(c + 1) & 1]);
          loadw(wbA, c + 1, wnxt);
          if (nf == 0) loadz(wzfAl, c + 1, zwn);
        }
        #pragma unroll
        for (int q = 0; q < 4; ++q) {
          int gr = arow * 16 + ((q*4 + kq) ^ (arow & 7));
          bf16x8 ah = *(const bf16x8*)(sb + gr*16);
          bf16x8 al = *(const bf16x8*)(sb + 16384 + gr*16);
          acc0 = __builtin_amdgcn_mfma_f32_16x16x32_bf16(ah, wcur[2*q],   acc0, 0, 0, 0);
          acc1 = __builtin_amdgcn_mfma_f32_16x16x32_bf16(ah, wcur[2*q+1], acc1, 0, 0, 0);
          acc2 = __builtin_amdgcn_mfma_f32_16x16x32_bf16(al, wcur[2*q],   acc2, 0, 0, 0);
          if (nf == 0) {
            az0 = __builtin_amdgcn_mfma_f32_16x16x32_bf16(ah, zwc[q], az0, 0, 0, 0);
            az1 = __builtin_amdgcn_mfma_f32_16x16x32_bf16(al, zwc[q], az1, 0, 0, 0);
          }
        }
        __syncthreads();   // waits vmcnt(0): stage c+1 landed; buf c reads done
        #pragma unroll
        for (int j = 0; j < 8; ++j) wcur[j] = wnxt[j];
        if (nf == 0) {
          #pragma unroll
          for (int q = 0; q < 4; ++q) zwc[q] = zwn[q];
        }
      }
      f32x4 accs = acc0 + acc1;
      accs = accs + acc2;
      {
        const int r0 = mf*16 + (lane >> 4)*4;
        const int cc = nf*16 + (lane & 15);
        ls_s[r0 + 0][cc] = accs[0];
        ls_s[r0 + 1][cc] = accs[1];
        ls_s[r0 + 2][cc] = accs[2];
        ls_s[r0 + 3][cc] = accs[3];
      }
      if (nf == 0) {
        int colc = lane & 15;
        int rbase = mf*16 + (lane >> 4)*4;
        if (colc == 0) {
          #pragma unroll
          for (int j = 0; j < 4; ++j) { zcols[0][rbase+j] = az0[j]; zcols[2][rbase+j] = az1[j]; }
        } else if (colc == 1) {
          #pragma unroll
          for (int j = 0; j < 4; ++j) zcols[1][rbase+j] = az0[j];
        }
      }
    }
    __syncthreads();
    if (tid < 64) {
      float s = bz1 + zcols[0][tid] + zcols[1][tid] + zcols[2][tid];
      z1n[tid] = fminf(fmaxf((s + 1.f) * 0.5f, 0.f), 1.f);
    }
    __syncthreads();
    {
      // epilogue layer 1 (zb==1): c' = z*ig + (1-z)*(f*c + ig); h' = o*tanh(c')
      float4 sv = *(const float4*)&ls_s[eb][4 * eu];
      float4 bb = *(const float4*)&bp1[c0 + 4 * eu];
      float f = sigmoidf_(sv.x + bb.x);
      float i = sigmoidf_(sv.y + bb.y);
      float o = sigmoidf_(sv.z + bb.z);
      float g = tanhf(sv.w + bb.w);
      float z = z1s[eb];
      float c = c1s[eb][eu];
      float ig = i * g;
      float cn = z * ig + (1.f - z) * fmaf(f, c, ig);
      float hn = o * tanhf(cn);
      c1s[eb][eu] = cn;
      float zn = z1n[eb];
      size_t ib = act_idx(NCHB, p, 0, erow, 512 + j0 + eu);       // phase B this step
      split_store(&actB[ib], &actB[ib + SPL_B], zn * hn);
      size_t ia = act_idx(NCHA, p ^ 1, 0, erow, j0 + eu);         // phase A next step
      split_store(&actA[ia], &actA[ia + SPL_A], (1.f - zn) * hn);
    }
    grid.sync();

    // ================= PHASE B (layer 2) =================
    if (tid < 64) z2s[tid] = z2n[tid];
    {
      bf16x8 wcur[8], wnxt[8], zwc[4], zwn[4];
      stage_chunk(actB, NCHB, p, 0, b0, nw, lane, stg[0]);
      loadw(wbB, 0, wcur);
      if (nf == 0) loadz(wzfBl, 0, zwc);
      f32x4 acc0 = {0.f,0.f,0.f,0.f}, acc1 = {0.f,0.f,0.f,0.f}, acc2 = {0.f,0.f,0.f,0.f};
      f32x4 az0  = {0.f,0.f,0.f,0.f}, az1  = {0.f,0.f,0.f,0.f};
      __syncthreads();
      for (int c = 0; c < NCHB; ++c) {
        char* sb = stg[c & 1];
        if (c + 1 < NCHB) {
          stage_chunk(actB, NCHB, p, c + 1, b0, nw, lane, stg[(c + 1) & 1]);
          loadw(wbB, c + 1, wnxt);
          if (nf == 0) loadz(wzfBl, c + 1, zwn);
        }
        #pragma unroll
        for (int q = 0; q < 4; ++q) {
          int gr = arow * 16 + ((q*4 + kq) ^ (arow & 7));
          bf16x8 ah = *(const bf16x8*)(sb + gr*16);
          bf16x8 al = *(const bf16x8*)(sb + 16384 + gr*16);
          acc0 = __builtin_amdgcn_mfma_f32_16x16x32_bf16(ah, wcur[2*q],   acc0, 0, 0, 0);
          acc1 = __builtin_amdgcn_mfma_f32_16x16x32_bf16(ah, wcur[2*q+1], acc1, 0, 0, 0);
          acc2 = __builtin_amdgcn_mfma_f32_16x16x32_bf16(al, wcur[2*q],   acc2, 0, 0, 0);
          if (nf == 0) {
            az0 = __builtin_amdgcn_mfma_f32_16x16x32_bf16(ah, zwc[q], az0, 0, 0, 0);
            az1 = __builtin_amdgcn_mfma_f32_16x16x32_bf16(al, zwc[q], az1, 0, 0, 0);
          }
        }
        __syncthreads();
        #pragma unroll
        for (int j = 0; j < 8; ++j) wcur[j] = wnxt[j];
        if (nf == 0) {
          #pragma unroll
          for (int q = 0; q < 4; ++q) zwc[q] = zwn[q];
        }
      }
      f32x4 accs = acc0 + acc1;
      accs = accs + acc2;
      {
        const int r0 = mf*16 + (lane >> 4)*4;
        const int cc = nf*16 + (lane & 15);
        ls_s[r0 + 0][cc] = accs[0];
        ls_s[r0 + 1][cc] = accs[1];
        ls_s[r0 + 2][cc] = accs[2];
        ls_s[r0 + 3][cc] = accs[3];
      }
      if (nf == 0) {
        int colc = lane & 15;
        int rbase = mf*16 + (lane >> 4)*4;
        if (colc == 0) {
          #pragma unroll
          for (int j = 0; j < 4; ++j) { zcols[0][rbase+j] = az0[j]; zcols[2][rbase+j] = az1[j]; }
        } else if (colc == 1) {
          #pragma unroll
          for (int j = 0; j < 4; ++j) zcols[1][rbase+j] = az0[j];
        }
      }
    }
    __syncthreads();
    if (tid < 64) {
      float s = bz2 + zcols[0][tid] + zcols[1][tid] + zcols[2][tid];
      z2n[tid] = fminf(fmaxf((s + 1.f) * 0.5f, 0.f), 1.f);
    }
    __syncthreads();
    {
      // epilogue layer 2: z = z2(t-1), zb = z1(t)
      float4 sv = *(const float4*)&ls_s[eb][4 * eu];
      float4 bb = *(const float4*)&bp2[c0 + 4 * eu];
      float f = sigmoidf_(sv.x + bb.x);
      float i = sigmoidf_(sv.y + bb.y);
      float o = sigmoidf_(sv.z + bb.z);
      float g = tanhf(sv.w + bb.w);
      float z   = z2s[eb];
      float zbv = z1n[eb];
      float c = c2s[eb][eu];
      float ig = i * g;
      float cn = z * ig + (1.f - z) * (1.f - zbv) * c + (1.f - z) * zbv * fmaf(f, c, ig);
      float tc = tanhf(cn);
      float ho = h2loc[eb][eu];
      float ot = o * tc;
      float hn = z * ot + (1.f - z) * (1.f - zbv) * ho + (1.f - z) * zbv * ot;
      c2s[eb][eu] = cn;
      h2loc[eb][eu] = hn;
      float z2new = z2n[eb];
      y[((size_t)erow * TT + t) * HH + j0 + eu] = hn * z2new;
      size_t ib = act_idx(NCHB, p ^ 1, 0, erow, j0 + eu);
      split_store(&actB[ib], &actB[ib + SPL_B], (1.f - z2new) * hn);
      size_t ia = act_idx(NCHA, p ^ 1, 0, erow, 512 + j0 + eu);
      split_store(&actA[ia], &actA[ia + SPL_A], z1n[eb] * hn);
      if (eu < 2 && t + 1 < TT) {
        int k = 1024 + nt * 2 + eu;
        float xv = x[((size_t)erow * TT + (t + 1)) * DD + (k - 1024)];
        size_t ix = act_idx(NCHA, p ^ 1, 0, erow, k);
        split_store(&actA[ix], &actA[ix + SPL_A], xv);
      }
    }
    grid.sync();
    p ^= 1;
  }
}

extern "C" void kernel_launch(void* const* d_in, const int* in_sizes, int n_in,
                              void* d_out, int out_size, void* d_ws, size_t ws_size,
                              hipStream_t stream) {
  const float* x     = (const float*)d_in[0];
  const float* U11_1 = (const float*)d_in[1];
  const float* U21_1 = (const float*)d_in[2];
  const float* W01_1 = (const float*)d_in[3];
  const float* b1    = (const float*)d_in[4];
  const float* U11_2 = (const float*)d_in[5];
  const float* W01_2 = (const float*)d_in[6];
  const float* b2    = (const float*)d_in[7];
  char*  wsb = (char*)d_ws;
  float* y   = (float*)d_out;
  (void)in_sizes; (void)n_in; (void)out_size; (void)ws_size;

  u16* wp    = (u16*)(wsb + OFF_WPA);
  u16* wzfa  = (u16*)(wsb + OFF_WZFA);
  u16* wzfb  = (u16*)(wsb + OFF_WZFB);
  float* bp1 = (float*)(wsb + OFF_BP1);
  float* bp2 = (float*)(wsb + OFF_BP2);
  float* bz  = (float*)(wsb + OFF_BZ);
  u16* acta  = (u16*)(wsb + OFF_ACTA);
  u16* actb  = (u16*)(wsb + OFF_ACTB);

  const unsigned NW = 128u*NKA*2u*512u + 128u*NKB*2u*512u;
  hipLaunchKernelGGL(pack_w, dim3((NW + 255u)/256u), dim3(256), 0, stream,
                     U11_1, U21_1, W01_1, U11_2, W01_2, wp);
  const unsigned NZ = 36u*512u + 32u*512u;
  hipLaunchKernelGGL(pack_wz, dim3((NZ + 255u)/256u), dim3(256), 0, stream,
                     U11_1, U21_1, W01_1, U11_2, W01_2, wzfa, wzfb);
  hipLaunchKernelGGL(pack_bias, dim3(17), dim3(256), 0, stream, b1, b2, bp1, bp2, bz);
  const unsigned NACT = 2u*2u*NCHA*256u*128u + 2u*2u*NCHB*256u*128u;
  hipLaunchKernelGGL(pack_act, dim3((NACT + 255u)/256u), dim3(256), 0, stream,
                     x, acta, actb);

  const float* xq = x;
  char* wsq = wsb;
  float* yq = y;
  void* kargs[] = { (void*)&xq, (void*)&wsq, (void*)&yq };
  hipLaunchCooperativeKernel((void*)hmlstm_kernel, dim3(256), dim3(512), kargs, 0, stream);
}

// Round 5
// 22503.975 us; speedup vs baseline: 10.0459x; 2.9656x over previous
//
#include <hip/hip_runtime.h>

#define TT 512
#define BB 256
#define DD 128
#define HH 512
#define KA 1152
#define KB 1024
#define NKA 36
#define NKB 32

// ---- ws byte-offset layout ----
#define OFF_WPA  0ull
#define SZ_WPA   (128ull*NKA*2ull*512ull*2ull)     // [colblk][kb][spl][lane][8] bf16
#define OFF_WPB  (OFF_WPA + SZ_WPA)
#define SZ_WPB   (128ull*NKB*2ull*512ull*2ull)
#define OFF_WZFA (OFF_WPB + SZ_WPB)                // [kb][lane][8] u16 (col0=hi,col1=lo)
#define SZ_WZFA  (36ull*512ull*2ull)
#define OFF_WZFB (OFF_WZFA + SZ_WZFA)
#define SZ_WZFB  (32ull*512ull*2ull)
#define OFF_BP1  (OFF_WZFB + SZ_WZFB)              // f32[2048] permuted bias l1
#define OFF_BP2  (OFF_BP1 + 8192ull)
#define OFF_BZ   (OFF_BP2 + 8192ull)               // bz1, bz2
#define OFF_CNT  (OFF_BZ + 256ull)                 // barrier counter
#define OFF_A1   (OFF_CNT + 256ull)                // 2 bufs x [2spl][64kg][256row][8] u16
#define OFF_A2   (OFF_A1 + 2ull*524288ull)         // 1 buf
#define OFF_B1   (OFF_A2 + 524288ull)              // 2 bufs
#define OFF_B2   (OFF_B1 + 2ull*524288ull)         // 1 buf
#define OFF_END  (OFF_B2 + 524288ull)

#define PLSTR 131072   // u16 stride between split planes within an act buffer

typedef __bf16 bf16x8 __attribute__((ext_vector_type(8)));
typedef float  f32x4  __attribute__((ext_vector_type(4)));
typedef unsigned short u16;

__device__ __forceinline__ u16 bf_bits(__bf16 h) {
  union { __bf16 b; u16 u; } cv; cv.b = h; return cv.u;
}
__device__ __forceinline__ float sigmoidf_(float v) { return 1.f / (1.f + __expf(-v)); }

// uncached (device-coherent) u16 store: sc0 sc1 -> write-through to coherence point
__device__ __forceinline__ void st_uc(u16* p, u16 v) {
  unsigned vv = v;
  asm volatile("global_store_short %0, %1, off sc0 sc1" :: "v"(p), "v"(vv) : "memory");
}
__device__ __forceinline__ void split_st_uc(u16* hi, u16* lo, float v) {
  __bf16 h = (__bf16)v;
  __bf16 l = (__bf16)(v - (float)h);
  st_uc(hi, bf_bits(h));
  st_uc(lo, bf_bits(l));
}

// global->LDS DMA, 16B/lane, cpol aux = SC0|NT|SC1 = 1|2|16 = 19 (device-coherent read)
__device__ __forceinline__ void gload_lds16_uc(const void* g, void* l) {
  __builtin_amdgcn_global_load_lds((const __attribute__((address_space(1))) unsigned int*)g,
                                   (__attribute__((address_space(3))) unsigned int*)l, 16, 0, 19);
}

// ---------------- pack kernels (weights identical to R3 layout) ----------------
__global__ void pack_w(const float* __restrict__ U11_1, const float* __restrict__ U21_1,
                       const float* __restrict__ W01_1, const float* __restrict__ U11_2,
                       const float* __restrict__ W01_2, u16* __restrict__ wp) {
  unsigned i = blockIdx.x * 256u + threadIdx.x;
  const unsigned NWA = 128u * NKA * 2u * 512u;
  const unsigned NWB = 128u * NKB * 2u * 512u;
  if (i >= NWA + NWB) return;
  float w; unsigned s;
  if (i < NWA) {
    unsigned lane = (i >> 3) & 63u, e = i & 7u; s = (i >> 9) & 1u;
    unsigned blk = i >> 10, kb = blk % NKA, colblk = blk / NKA;
    unsigned c = colblk * 16u + (lane & 15u);
    unsigned n = (c & 3u) * 512u + (c >> 2);
    unsigned k = kb * 32u + (lane >> 4) * 8u + e;
    w = (k < 512u)  ? U11_1[n * 512u + k]
      : (k < 1024u) ? U21_1[n * 512u + (k - 512u)]
                    : W01_1[n * 128u + (k - 1024u)];
  } else {
    unsigned j = i - NWA;
    unsigned lane = (j >> 3) & 63u, e = j & 7u; s = (j >> 9) & 1u;
    unsigned blk = j >> 10, kb = blk % NKB, colblk = blk / NKB;
    unsigned c = colblk * 16u + (lane & 15u);
    unsigned n = (c & 3u) * 512u + (c >> 2);
    unsigned k = kb * 32u + (lane >> 4) * 8u + e;
    w = (k < 512u) ? U11_2[n * 512u + k] : W01_2[n * 512u + (k - 512u)];
  }
  __bf16 hi = (__bf16)w;
  __bf16 v = s ? (__bf16)(w - (float)hi) : hi;
  wp[i] = bf_bits(v);
}

__global__ void pack_wz(const float* __restrict__ U11_1, const float* __restrict__ U21_1,
                        const float* __restrict__ W01_1, const float* __restrict__ U11_2,
                        const float* __restrict__ W01_2,
                        u16* __restrict__ wzfa, u16* __restrict__ wzfb) {
  unsigned i = blockIdx.x * 256u + threadIdx.x;
  const unsigned NZA = 36u * 512u, NZB = 32u * 512u;
  if (i >= NZA + NZB) return;
  const bool isA = i < NZA;
  unsigned j = isA ? i : i - NZA;
  unsigned e = j & 7u, lane = (j >> 3) & 63u, kb = j >> 9;
  unsigned col = lane & 15u;
  unsigned k = kb * 32u + (lane >> 4) * 8u + e;
  float wz;
  if (isA) {
    wz = (k < 512u)  ? U11_1[2048u*512u + k]
       : (k < 1024u) ? U21_1[2048u*512u + (k-512u)]
                     : W01_1[2048u*128u + (k-1024u)];
  } else {
    wz = (k < 512u) ? U11_2[2048u*512u + k] : W01_2[2048u*512u + (k-512u)];
  }
  u16 out = 0;
  if (col == 0u) out = bf_bits((__bf16)wz);
  else if (col == 1u) { __bf16 h = (__bf16)wz; out = bf_bits((__bf16)(wz - (float)h)); }
  (isA ? wzfa : wzfb)[j] = out;
}

__global__ void pack_bias(const float* __restrict__ b1, const float* __restrict__ b2,
                          float* __restrict__ bp1, float* __restrict__ bp2,
                          float* __restrict__ bz) {
  unsigned i = blockIdx.x * 256u + threadIdx.x;
  if (i < 2048u) bp1[i] = b1[(i & 3u)*512u + (i >> 2)];
  else if (i < 4096u) { unsigned c = i - 2048u; bp2[c] = b2[(c & 3u)*512u + (c >> 2)]; }
  else if (i == 4096u) bz[0] = b1[2048];
  else if (i == 4097u) bz[1] = b2[2048];
}

// zero act buffers + barrier counter
__global__ void init_zero(char* __restrict__ wsb) {
  size_t i = (size_t)blockIdx.x * 256u + threadIdx.x;
  size_t n = (OFF_END - OFF_CNT) / 4u;
  if (i < n) ((unsigned*)(wsb + OFF_CNT))[i] = 0u;
}

// ---------------- main persistent kernel ----------------
// 256 WGs x 512 threads. WG = 16 rows (mg) x 128 cols (ntg), for BOTH layers.
// XCD x (bid%8) hosts ntg {2x,2x+1} for all 16 mgs -> 2.2 MB L2-resident weights.
// Acts exchanged via device-coherent (sc0 sc1) stores + coherent global_load_lds;
// custom fence-free grid barrier (no L2 invalidation, ever).
__global__ __launch_bounds__(512, 2) void hmlstm_kernel(const float* __restrict__ x,
                                                        char* __restrict__ wsb,
                                                        float* __restrict__ y) {
  const int tid  = threadIdx.x;
  const int lane = tid & 63;
  const int nw   = __builtin_amdgcn_readfirstlane(tid >> 6);
  const int bid  = blockIdx.x;
  const int ntg  = (bid & 7) * 2 + (bid >> 7);   // 0..15
  const int mg   = (bid >> 3) & 15;              // 0..15
  const int b0   = mg * 16;

  const u16* wpA  = (const u16*)(wsb + OFF_WPA);
  const u16* wpB  = (const u16*)(wsb + OFF_WPB);
  const u16* wzfA = (const u16*)(wsb + OFF_WZFA);
  const u16* wzfB = (const u16*)(wsb + OFF_WZFB);
  const float* bp1 = (const float*)(wsb + OFF_BP1);
  const float* bp2 = (const float*)(wsb + OFF_BP2);
  const float bz1 = ((const float*)(wsb + OFF_BZ))[0];
  const float bz2 = ((const float*)(wsb + OFF_BZ))[1];
  unsigned* cnt = (unsigned*)(wsb + OFF_CNT);
  u16* A1b[2] = { (u16*)(wsb + OFF_A1), (u16*)(wsb + OFF_A1 + 524288ull) };
  u16* A2b    =   (u16*)(wsb + OFF_A2);
  u16* B1b[2] = { (u16*)(wsb + OFF_B1), (u16*)(wsb + OFF_B1 + 524288ull) };
  u16* B2b    =   (u16*)(wsb + OFF_B2);

  __shared__ u16 stgA[2][2][16][64][8];   // [arr][spl][kb16][lane][8] = 64 KB
  __shared__ u16 stgB[2][2][16][64][8];   // 64 KB
  __shared__ float ls_s[16][132];
  __shared__ float zp[3][16];
  __shared__ float znew[16];

  const int kgp   = lane >> 4;    // k-slot 0..3
  const int row16 = lane & 15;    // frag row 0..15
  const int er = tid >> 5, eu = tid & 31;   // epilogue (row, unit-in-WG)
  const int erow = b0 + er;
  const int ku = ntg * 32 + eu;             // global hidden-unit index 0..511
  const size_t pidx = ((size_t)(ku >> 3) * 256 + erow) * 8 + (ku & 7);

  const u16* wbA = wpA + (size_t)(ntg*8 + nw) * (NKA*1024u) + lane*8;
  const u16* wbB = wpB + (size_t)(ntg*8 + nw) * (NKB*1024u) + lane*8;
  const u16* wzA = wzfA + lane*8;
  const u16* wzB = wzfB + lane*8;

  // per-thread recurrent state (row er, unit eu fixed across steps)
  float c1r = 0.f, c2r = 0.f, h2r = 0.f;
  float z1p = 0.f, z2p = 0.f, z1c = 0.f;
  unsigned bar_tgt = 256u;
  int p = 0;

  for (int t = 0; t < TT; ++t) {
    // ======== PHASE A ========
    if (t == 0) {   // no prior prefetch of A1[0]
      for (int j = 0; j < 4; ++j) {
        int i = nw*4 + j; int spl = i >> 4, kq = i & 15;
        const u16* src = A1b[0] + spl*PLSTR + ((size_t)((kq*4 + kgp)*256 + b0 + row16))*8;
        gload_lds16_uc(src, &stgA[0][spl][kq][0][0]);
      }
    }
    for (int j = 0; j < 4; ++j) {     // stage A2 half (ready since barrier#2 of t-1)
      int i = nw*4 + j; int spl = i >> 4, kq = i & 15;
      const u16* src = A2b + spl*PLSTR + ((size_t)((kq*4 + kgp)*256 + b0 + row16))*8;
      gload_lds16_uc(src, &stgA[1][spl][kq][0][0]);
    }
    // x fragments on the fly (cached f32 reads, static input)
    bf16x8 xah[4], xal[4];
    {
      const float* xp = x + ((size_t)(b0 + row16) * TT + t) * DD + kgp*8;
      for (int k4 = 0; k4 < 4; ++k4) {
        float4 v0 = *(const float4*)(xp + k4*32);
        float4 v1 = *(const float4*)(xp + k4*32 + 4);
        float vv[8] = {v0.x,v0.y,v0.z,v0.w,v1.x,v1.y,v1.z,v1.w};
        for (int e = 0; e < 8; ++e) {
          __bf16 h = (__bf16)vv[e];
          xah[k4][e] = h;
          xal[k4][e] = (__bf16)(vv[e] - (float)h);
        }
      }
    }
    __syncthreads();   // drain staging DMAs (vmcnt0 per wave) + WG barrier

    {
      f32x4 acc0={0,0,0,0}, acc1={0,0,0,0}, acc2={0,0,0,0};
      f32x4 az={0,0,0,0};
      #pragma unroll 4
      for (int kb = 0; kb < 32; ++kb) {
        const u16* sa = &stgA[kb>>4][0][kb&15][lane][0];
        bf16x8 ah = *(const bf16x8*)sa;
        bf16x8 al = *(const bf16x8*)(sa + 8192);
        bf16x8 wh = *(const bf16x8*)(wbA + kb*1024);
        bf16x8 wl = *(const bf16x8*)(wbA + kb*1024 + 512);
        acc0 = __builtin_amdgcn_mfma_f32_16x16x32_bf16(ah, wh, acc0, 0, 0, 0);
        acc1 = __builtin_amdgcn_mfma_f32_16x16x32_bf16(ah, wl, acc1, 0, 0, 0);
        acc2 = __builtin_amdgcn_mfma_f32_16x16x32_bf16(al, wh, acc2, 0, 0, 0);
        if (nw == 0) { bf16x8 zf = *(const bf16x8*)(wzA + kb*512);
                       az = __builtin_amdgcn_mfma_f32_16x16x32_bf16(ah, zf, az, 0, 0, 0); }
        if (nw == 1) { bf16x8 zf = *(const bf16x8*)(wzA + kb*512);
                       az = __builtin_amdgcn_mfma_f32_16x16x32_bf16(al, zf, az, 0, 0, 0); }
      }
      for (int k4 = 0; k4 < 4; ++k4) {
        int kb = 32 + k4;
        bf16x8 ah = xah[k4], al = xal[k4];
        bf16x8 wh = *(const bf16x8*)(wbA + kb*1024);
        bf16x8 wl = *(const bf16x8*)(wbA + kb*1024 + 512);
        acc0 = __builtin_amdgcn_mfma_f32_16x16x32_bf16(ah, wh, acc0, 0, 0, 0);
        acc1 = __builtin_amdgcn_mfma_f32_16x16x32_bf16(ah, wl, acc1, 0, 0, 0);
        acc2 = __builtin_amdgcn_mfma_f32_16x16x32_bf16(al, wh, acc2, 0, 0, 0);
        if (nw == 0) { bf16x8 zf = *(const bf16x8*)(wzA + kb*512);
                       az = __builtin_amdgcn_mfma_f32_16x16x32_bf16(ah, zf, az, 0, 0, 0); }
        if (nw == 1) { bf16x8 zf = *(const bf16x8*)(wzA + kb*512);
                       az = __builtin_amdgcn_mfma_f32_16x16x32_bf16(al, zf, az, 0, 0, 0); }
      }
      f32x4 accs = acc0 + acc1; accs = accs + acc2;
      int cc = nw*16 + (lane & 15);
      int r0 = (lane >> 4) * 4;
      ls_s[r0+0][cc] = accs[0]; ls_s[r0+1][cc] = accs[1];
      ls_s[r0+2][cc] = accs[2]; ls_s[r0+3][cc] = accs[3];
      if (nw == 0 && (lane&15) == 0) {
        for (int j2 = 0; j2 < 4; ++j2) zp[0][r0+j2] = az[j2];
      }
      if (nw == 0 && (lane&15) == 1) {
        for (int j2 = 0; j2 < 4; ++j2) zp[1][r0+j2] = az[j2];
      }
      if (nw == 1 && (lane&15) == 0) {
        for (int j2 = 0; j2 < 4; ++j2) zp[2][r0+j2] = az[j2];
      }
    }
    __syncthreads();
    if (tid < 16) {
      float s = zp[0][tid] + zp[1][tid] + zp[2][tid] + bz1;
      znew[tid] = fminf(fmaxf((s + 1.f)*0.5f, 0.f), 1.f);
    }
    __syncthreads();
    {
      // epilogue layer 1 (zb==1): c' = z*ig + (1-z)*(f*c + ig); h' = o*tanh(c')
      float4 sv = *(const float4*)&ls_s[er][4*eu];
      float4 bb = *(const float4*)&bp1[ntg*128 + 4*eu];
      float f = sigmoidf_(sv.x + bb.x);
      float i = sigmoidf_(sv.y + bb.y);
      float o = sigmoidf_(sv.z + bb.z);
      float g = tanhf(sv.w + bb.w);
      float z = z1p;
      float ig = i * g;
      float cn = z * ig + (1.f - z) * fmaf(f, c1r, ig);
      float hn = o * tanhf(cn);
      c1r = cn;
      float zn = znew[er];
      z1c = zn; z1p = zn;
      u16* a1w = A1b[p ^ 1];
      split_st_uc(a1w + pidx, a1w + PLSTR + pidx, (1.f - zn) * hn);   // A next step
      split_st_uc(B2b + pidx, B2b + PLSTR + pidx, zn * hn);           // B this step
    }
    __syncthreads();   // drains uncached stores (vmcnt0) before arrival
    // prefetch B1[p] (written before barrier#2 of t-1 -> globally stable)
    for (int j = 0; j < 4; ++j) {
      int i = nw*4 + j; int spl = i >> 4, kq = i & 15;
      const u16* src = B1b[p] + spl*PLSTR + ((size_t)((kq*4 + kgp)*256 + b0 + row16))*8;
      gload_lds16_uc(src, &stgB[0][spl][kq][0][0]);
    }
    if (tid == 0) {
      __hip_atomic_fetch_add(cnt, 1u, __ATOMIC_RELAXED, __HIP_MEMORY_SCOPE_AGENT);
      while (__hip_atomic_load(cnt, __ATOMIC_RELAXED, __HIP_MEMORY_SCOPE_AGENT) < bar_tgt)
        __builtin_amdgcn_s_sleep(4);
    }
    bar_tgt += 256u;
    __builtin_amdgcn_s_barrier();   // raw release: prefetches stay in flight

    // ======== PHASE B ========
    for (int j = 0; j < 4; ++j) {   // stage B2 (written by A-epi, fenced by barrier#1)
      int i = nw*4 + j; int spl = i >> 4, kq = i & 15;
      const u16* src = B2b + spl*PLSTR + ((size_t)((kq*4 + kgp)*256 + b0 + row16))*8;
      gload_lds16_uc(src, &stgB[1][spl][kq][0][0]);
    }
    __syncthreads();

    {
      f32x4 acc0={0,0,0,0}, acc1={0,0,0,0}, acc2={0,0,0,0};
      f32x4 az={0,0,0,0};
      #pragma unroll 4
      for (int kb = 0; kb < 32; ++kb) {
        const u16* sa = &stgB[kb>>4][0][kb&15][lane][0];
        bf16x8 ah = *(const bf16x8*)sa;
        bf16x8 al = *(const bf16x8*)(sa + 8192);
        bf16x8 wh = *(const bf16x8*)(wbB + kb*1024);
        bf16x8 wl = *(const bf16x8*)(wbB + kb*1024 + 512);
        acc0 = __builtin_amdgcn_mfma_f32_16x16x32_bf16(ah, wh, acc0, 0, 0, 0);
        acc1 = __builtin_amdgcn_mfma_f32_16x16x32_bf16(ah, wl, acc1, 0, 0, 0);
        acc2 = __builtin_amdgcn_mfma_f32_16x16x32_bf16(al, wh, acc2, 0, 0, 0);
        if (nw == 0) { bf16x8 zf = *(const bf16x8*)(wzB + kb*512);
                       az = __builtin_amdgcn_mfma_f32_16x16x32_bf16(ah, zf, az, 0, 0, 0); }
        if (nw == 1) { bf16x8 zf = *(const bf16x8*)(wzB + kb*512);
                       az = __builtin_amdgcn_mfma_f32_16x16x32_bf16(al, zf, az, 0, 0, 0); }
      }
      f32x4 accs = acc0 + acc1; accs = accs + acc2;
      int cc = nw*16 + (lane & 15);
      int r0 = (lane >> 4) * 4;
      ls_s[r0+0][cc] = accs[0]; ls_s[r0+1][cc] = accs[1];
      ls_s[r0+2][cc] = accs[2]; ls_s[r0+3][cc] = accs[3];
      if (nw == 0 && (lane&15) == 0) {
        for (int j2 = 0; j2 < 4; ++j2) zp[0][r0+j2] = az[j2];
      }
      if (nw == 0 && (lane&15) == 1) {
        for (int j2 = 0; j2 < 4; ++j2) zp[1][r0+j2] = az[j2];
      }
      if (nw == 1 && (lane&15) == 0) {
        for (int j2 = 0; j2 < 4; ++j2) zp[2][r0+j2] = az[j2];
      }
    }
    __syncthreads();
    if (tid < 16) {
      float s = zp[0][tid] + zp[1][tid] + zp[2][tid] + bz2;
      znew[tid] = fminf(fmaxf((s + 1.f)*0.5f, 0.f), 1.f);
    }
    __syncthreads();
    {
      // epilogue layer 2: z = z2(t-1), zb = z1(t)
      float4 sv = *(const float4*)&ls_s[er][4*eu];
      float4 bb = *(const float4*)&bp2[ntg*128 + 4*eu];
      float f = sigmoidf_(sv.x + bb.x);
      float i = sigmoidf_(sv.y + bb.y);
      float o = sigmoidf_(sv.z + bb.z);
      float g = tanhf(sv.w + bb.w);
      float z = z2p, zb = z1c;
      float ig = i * g;
      float cn = z*ig + (1.f-z)*(1.f-zb)*c2r + (1.f-z)*zb*fmaf(f, c2r, ig);
      float tc = tanhf(cn);
      float ot = o * tc;
      float hn = z*ot + (1.f-z)*(1.f-zb)*h2r + (1.f-z)*zb*ot;
      c2r = cn; h2r = hn;
      float z2n_ = znew[er];
      z2p = z2n_;
      y[((size_t)erow * TT + t) * HH + ku] = hn * z2n_;
      u16* b1w = B1b[p ^ 1];
      split_st_uc(b1w + pidx, b1w + PLSTR + pidx, (1.f - z2n_) * hn);  // B next step
      split_st_uc(A2b + pidx, A2b + PLSTR + pidx, z1c * hn);           // A next step
    }
    __syncthreads();   // drain stores
    // prefetch A1[p^1] (written by A-epi of THIS step, fenced by barrier#1)
    for (int j = 0; j < 4; ++j) {
      int i = nw*4 + j; int spl = i >> 4, kq = i & 15;
      const u16* src = A1b[p ^ 1] + spl*PLSTR + ((size_t)((kq*4 + kgp)*256 + b0 + row16))*8;
      gload_lds16_uc(src, &stgA[0][spl][kq][0][0]);
    }
    if (tid == 0) {
      __hip_atomic_fetch_add(cnt, 1u, __ATOMIC_RELAXED, __HIP_MEMORY_SCOPE_AGENT);
      while (__hip_atomic_load(cnt, __ATOMIC_RELAXED, __HIP_MEMORY_SCOPE_AGENT) < bar_tgt)
        __builtin_amdgcn_s_sleep(4);
    }
    bar_tgt += 256u;
    __builtin_amdgcn_s_barrier();

    p ^= 1;
  }
}

extern "C" void kernel_launch(void* const* d_in, const int* in_sizes, int n_in,
                              void* d_out, int out_size, void* d_ws, size_t ws_size,
                              hipStream_t stream) {
  const float* x     = (const float*)d_in[0];
  const float* U11_1 = (const float*)d_in[1];
  const float* U21_1 = (const float*)d_in[2];
  const float* W01_1 = (const float*)d_in[3];
  const float* b1    = (const float*)d_in[4];
  const float* U11_2 = (const float*)d_in[5];
  const float* W01_2 = (const float*)d_in[6];
  const float* b2    = (const float*)d_in[7];
  char*  wsb = (char*)d_ws;
  float* y   = (float*)d_out;
  (void)in_sizes; (void)n_in; (void)out_size; (void)ws_size;

  u16* wp    = (u16*)(wsb + OFF_WPA);
  u16* wzfa  = (u16*)(wsb + OFF_WZFA);
  u16* wzfb  = (u16*)(wsb + OFF_WZFB);
  float* bp1 = (float*)(wsb + OFF_BP1);
  float* bp2 = (float*)(wsb + OFF_BP2);
  float* bz  = (float*)(wsb + OFF_BZ);

  const unsigned NW = 128u*NKA*2u*512u + 128u*NKB*2u*512u;
  hipLaunchKernelGGL(pack_w, dim3((NW + 255u)/256u), dim3(256), 0, stream,
                     U11_1, U21_1, W01_1, U11_2, W01_2, wp);
  const unsigned NZ = 36u*512u + 32u*512u;
  hipLaunchKernelGGL(pack_wz, dim3((NZ + 255u)/256u), dim3(256), 0, stream,
                     U11_1, U21_1, W01_1, U11_2, W01_2, wzfa, wzfb);
  hipLaunchKernelGGL(pack_bias, dim3(17), dim3(256), 0, stream, b1, b2, bp1, bp2, bz);
  const unsigned n_zero_words = (unsigned)((OFF_END - OFF_CNT) / 4u);
  hipLaunchKernelGGL(init_zero, dim3((n_zero_words + 255u)/256u), dim3(256), 0, stream, wsb);

  const float* xq = x;
  char* wsq = wsb;
  float* yq = y;
  void* kargs[] = { (void*)&xq, (void*)&wsq, (void*)&yq };
  hipLaunchCooperativeKernel((void*)hmlstm_kernel, dim3(256), dim3(512), kargs, 0, stream);
}

// Round 7
// 15588.986 us; speedup vs baseline: 14.5021x; 1.4436x over previous
//
#include <hip/hip_runtime.h>

#define TT 512
#define BB 256
#define DD 128
#define HH 512
#define KA 1152
#define KB 1024
#define NKA 36
#define NKB 32

// ---- ws byte-offset layout ----
#define OFF_WPA  0ull
#define SZ_WPA   (128ull*NKA*2ull*512ull*2ull)     // [colblk][kb][spl][lane][8] bf16
#define OFF_WPB  (OFF_WPA + SZ_WPA)
#define SZ_WPB   (128ull*NKB*2ull*512ull*2ull)
#define OFF_WZFA (OFF_WPB + SZ_WPB)                // [kb][lane][8] u16 (col0=hi,col1=lo)
#define SZ_WZFA  (36ull*512ull*2ull)
#define OFF_WZFB (OFF_WZFA + SZ_WZFA)
#define SZ_WZFB  (32ull*512ull*2ull)
#define OFF_BP1  (OFF_WZFB + SZ_WZFB)              // f32[2048] permuted bias l1
#define OFF_BP2  (OFF_BP1 + 8192ull)
#define OFF_BZ   (OFF_BP2 + 8192ull)               // bz1, bz2
#define OFF_CNT  (OFF_BZ + 256ull)                 // 16 group-barrier counters, 256B apart
#define OFF_A1   (OFF_CNT + 4096ull)               // 2 bufs x [2spl][64kg][256row][8] u16
#define OFF_A2   (OFF_A1 + 2ull*524288ull)         // 1 buf
#define OFF_B1   (OFF_A2 + 524288ull)              // 2 bufs
#define OFF_B2   (OFF_B1 + 2ull*524288ull)         // 1 buf
#define OFF_END  (OFF_B2 + 524288ull)

#define PLSTR 131072   // u16 stride between split planes within an act buffer

typedef __bf16 bf16x8 __attribute__((ext_vector_type(8)));
typedef float  f32x4  __attribute__((ext_vector_type(4)));
typedef unsigned short u16;

__device__ __forceinline__ u16 bf_bits(__bf16 h) {
  union { __bf16 b; u16 u; } cv; cv.b = h; return cv.u;
}
__device__ __forceinline__ float sigmoidf_(float v) { return 1.f / (1.f + __expf(-v)); }

// uncached (device-coherent) u16 store: sc0 sc1 -> write-through to coherence point
__device__ __forceinline__ void st_uc(u16* p, u16 v) {
  unsigned vv = v;
  asm volatile("global_store_short %0, %1, off sc0 sc1" :: "v"(p), "v"(vv) : "memory");
}
__device__ __forceinline__ void split_st_uc(u16* hi, u16* lo, float v) {
  __bf16 h = (__bf16)v;
  __bf16 l = (__bf16)(v - (float)h);
  st_uc(hi, bf_bits(h));
  st_uc(lo, bf_bits(l));
}
// explicit drain of ALL outstanding VMEM ops of this wave (inline-asm stores are
// invisible to the compiler's waitcnt scoreboard -- __syncthreads alone is not enough)
__device__ __forceinline__ void drain_vmem() {
  asm volatile("s_waitcnt vmcnt(0)" ::: "memory");
}

// global->LDS DMA, 16B/lane, cpol aux = SC0|NT|SC1 = 19 (device-coherent read)
__device__ __forceinline__ void gload_lds16_uc(const void* g, void* l) {
  __builtin_amdgcn_global_load_lds((const __attribute__((address_space(1))) unsigned int*)g,
                                   (__attribute__((address_space(3))) unsigned int*)l, 16, 0, 19);
}

// ---------------- pack kernels (identical layouts to R5) ----------------
__global__ void pack_w(const float* __restrict__ U11_1, const float* __restrict__ U21_1,
                       const float* __restrict__ W01_1, const float* __restrict__ U11_2,
                       const float* __restrict__ W01_2, u16* __restrict__ wp) {
  unsigned i = blockIdx.x * 256u + threadIdx.x;
  const unsigned NWA = 128u * NKA * 2u * 512u;
  const unsigned NWB = 128u * NKB * 2u * 512u;
  if (i >= NWA + NWB) return;
  float w; unsigned s;
  if (i < NWA) {
    unsigned lane = (i >> 3) & 63u, e = i & 7u; s = (i >> 9) & 1u;
    unsigned blk = i >> 10, kb = blk % NKA, colblk = blk / NKA;
    unsigned c = colblk * 16u + (lane & 15u);
    unsigned n = (c & 3u) * 512u + (c >> 2);
    unsigned k = kb * 32u + (lane >> 4) * 8u + e;
    w = (k < 512u)  ? U11_1[n * 512u + k]
      : (k < 1024u) ? U21_1[n * 512u + (k - 512u)]
                    : W01_1[n * 128u + (k - 1024u)];
  } else {
    unsigned j = i - NWA;
    unsigned lane = (j >> 3) & 63u, e = j & 7u; s = (j >> 9) & 1u;
    unsigned blk = j >> 10, kb = blk % NKB, colblk = blk / NKB;
    unsigned c = colblk * 16u + (lane & 15u);
    unsigned n = (c & 3u) * 512u + (c >> 2);
    unsigned k = kb * 32u + (lane >> 4) * 8u + e;
    w = (k < 512u) ? U11_2[n * 512u + k] : W01_2[n * 512u + (k - 512u)];
  }
  __bf16 hi = (__bf16)w;
  __bf16 v = s ? (__bf16)(w - (float)hi) : hi;
  wp[i] = bf_bits(v);
}

__global__ void pack_wz(const float* __restrict__ U11_1, const float* __restrict__ U21_1,
                        const float* __restrict__ W01_1, const float* __restrict__ U11_2,
                        const float* __restrict__ W01_2,
                        u16* __restrict__ wzfa, u16* __restrict__ wzfb) {
  unsigned i = blockIdx.x * 256u + threadIdx.x;
  const unsigned NZA = 36u * 512u, NZB = 32u * 512u;
  if (i >= NZA + NZB) return;
  const bool isA = i < NZA;
  unsigned j = isA ? i : i - NZA;
  unsigned e = j & 7u, lane = (j >> 3) & 63u, kb = j >> 9;
  unsigned col = lane & 15u;
  unsigned k = kb * 32u + (lane >> 4) * 8u + e;
  float wz;
  if (isA) {
    wz = (k < 512u)  ? U11_1[2048u*512u + k]
       : (k < 1024u) ? U21_1[2048u*512u + (k-512u)]
                     : W01_1[2048u*128u + (k-1024u)];
  } else {
    wz = (k < 512u) ? U11_2[2048u*512u + k] : W01_2[2048u*512u + (k-512u)];
  }
  u16 out = 0;
  if (col == 0u) out = bf_bits((__bf16)wz);
  else if (col == 1u) { __bf16 h = (__bf16)wz; out = bf_bits((__bf16)(wz - (float)h)); }
  (isA ? wzfa : wzfb)[j] = out;
}

__global__ void pack_bias(const float* __restrict__ b1, const float* __restrict__ b2,
                          float* __restrict__ bp1, float* __restrict__ bp2,
                          float* __restrict__ bz) {
  unsigned i = blockIdx.x * 256u + threadIdx.x;
  if (i < 2048u) bp1[i] = b1[(i & 3u)*512u + (i >> 2)];
  else if (i < 4096u) { unsigned c = i - 2048u; bp2[c] = b2[(c & 3u)*512u + (c >> 2)]; }
  else if (i == 4096u) bz[0] = b1[2048];
  else if (i == 4097u) bz[1] = b2[2048];
}

// zero act buffers + barrier counters
__global__ void init_zero(char* __restrict__ wsb) {
  size_t i = (size_t)blockIdx.x * 256u + threadIdx.x;
  size_t n = (OFF_END - OFF_CNT) / 4u;
  if (i < n) ((unsigned*)(wsb + OFF_CNT))[i] = 0u;
}

// ---------------- main persistent kernel ----------------
// 256 WGs x 512 threads. WG = 16 rows (mg) x 128 cols (ntg).
// XCD x (bid&7) hosts ntg {2x,2x+1} for all 16 mgs -> 2.2 MB L2-resident weights.
// Cross-WG deps exist ONLY within an mg-group (16 WGs sharing rows) -> 16
// independent group barriers (one counter per mg, own cache line). No L2
// invalidation anywhere; acts via device-coherent stores + coherent DMA reads.
// All inline-asm stores are explicitly drained (vmcnt0) before barrier arrival.
__global__ __launch_bounds__(512, 2) void hmlstm_kernel(const float* __restrict__ x,
                                                        char* __restrict__ wsb,
                                                        float* __restrict__ y) {
  const int tid  = threadIdx.x;
  const int lane = tid & 63;
  const int nw   = __builtin_amdgcn_readfirstlane(tid >> 6);
  const int bid  = blockIdx.x;
  const int ntg  = (bid & 7) * 2 + (bid >> 7);   // 0..15
  const int mg   = (bid >> 3) & 15;              // 0..15
  const int b0   = mg * 16;

  const u16* wpA  = (const u16*)(wsb + OFF_WPA);
  const u16* wpB  = (const u16*)(wsb + OFF_WPB);
  const u16* wzfA = (const u16*)(wsb + OFF_WZFA);
  const u16* wzfB = (const u16*)(wsb + OFF_WZFB);
  const float* bp1 = (const float*)(wsb + OFF_BP1);
  const float* bp2 = (const float*)(wsb + OFF_BP2);
  const float bz1 = ((const float*)(wsb + OFF_BZ))[0];
  const float bz2 = ((const float*)(wsb + OFF_BZ))[1];
  unsigned* cnt = (unsigned*)(wsb + OFF_CNT) + mg * 64;   // own 256B line
  u16* A1b[2] = { (u16*)(wsb + OFF_A1), (u16*)(wsb + OFF_A1 + 524288ull) };
  u16* A2b    =   (u16*)(wsb + OFF_A2);
  u16* B1b[2] = { (u16*)(wsb + OFF_B1), (u16*)(wsb + OFF_B1 + 524288ull) };
  u16* B2b    =   (u16*)(wsb + OFF_B2);

  __shared__ u16 stgA[2][2][16][64][8];   // 64 KB
  __shared__ u16 stgB[2][2][16][64][8];   // 64 KB
  __shared__ float ls_s[16][132];
  __shared__ float zp[3][16];

  const int kgp   = lane >> 4;    // k-slot 0..3
  const int row16 = lane & 15;    // frag row 0..15
  const int er = tid >> 5, eu = tid & 31;   // epilogue (row, unit-in-WG)
  const int erow = b0 + er;
  const int ku = ntg * 32 + eu;             // global hidden-unit index
  const size_t pidx = ((size_t)(ku >> 3) * 256 + erow) * 8 + (ku & 7);

  const u16* wbA = wpA + (size_t)(ntg*8 + nw) * (NKA*1024u) + lane*8;
  const u16* wbB = wpB + (size_t)(ntg*8 + nw) * (NKB*1024u) + lane*8;
  const u16* wzA = wzfA + lane*8;
  const u16* wzB = wzfB + lane*8;

  // per-thread recurrent state (row er, unit eu fixed across steps)
  float c1r = 0.f, c2r = 0.f, h2r = 0.f;
  float z1p = 0.f, z2p = 0.f, z1c = 0.f;
  unsigned bar_tgt = 16u;
  int p = 0;

  for (int t = 0; t < TT; ++t) {
    // ======== PHASE A ========
    if (t == 0) {   // no prior prefetch of A1[0]
      for (int j = 0; j < 4; ++j) {
        int i = nw*4 + j; int spl = i >> 4, kq = i & 15;
        const u16* src = A1b[0] + spl*PLSTR + ((size_t)((kq*4 + kgp)*256 + b0 + row16))*8;
        gload_lds16_uc(src, &stgA[0][spl][kq][0][0]);
      }
    }
    for (int j = 0; j < 4; ++j) {     // stage A2 half (fenced by barrier#2 of t-1)
      int i = nw*4 + j; int spl = i >> 4, kq = i & 15;
      const u16* src = A2b + spl*PLSTR + ((size_t)((kq*4 + kgp)*256 + b0 + row16))*8;
      gload_lds16_uc(src, &stgA[1][spl][kq][0][0]);
    }
    for (int j = 0; j < 4; ++j) {     // prefetch B1[p] (fenced by barrier#2 of t-1)
      int i = nw*4 + j; int spl = i >> 4, kq = i & 15;
      const u16* src = B1b[p] + spl*PLSTR + ((size_t)((kq*4 + kgp)*256 + b0 + row16))*8;
      gload_lds16_uc(src, &stgB[0][spl][kq][0][0]);
    }
    // x fragments on the fly (cached f32 reads, static input)
    bf16x8 xah[4], xal[4];
    {
      const float* xp = x + ((size_t)(b0 + row16) * TT + t) * DD + kgp*8;
      for (int k4 = 0; k4 < 4; ++k4) {
        float4 v0 = *(const float4*)(xp + k4*32);
        float4 v1 = *(const float4*)(xp + k4*32 + 4);
        float vv[8] = {v0.x,v0.y,v0.z,v0.w,v1.x,v1.y,v1.z,v1.w};
        for (int e = 0; e < 8; ++e) {
          __bf16 h = (__bf16)vv[e];
          xah[k4][e] = h;
          xal[k4][e] = (__bf16)(vv[e] - (float)h);
        }
      }
    }
    __syncthreads();   // drain staging DMAs + WG barrier

    {
      f32x4 acc0={0,0,0,0}, acc1={0,0,0,0}, acc2={0,0,0,0};
      f32x4 az={0,0,0,0};
      #pragma unroll 4
      for (int kb = 0; kb < 32; ++kb) {
        const u16* sa = &stgA[kb>>4][0][kb&15][lane][0];
        bf16x8 ah = *(const bf16x8*)sa;
        bf16x8 al = *(const bf16x8*)(sa + 8192);
        bf16x8 wh = *(const bf16x8*)(wbA + kb*1024);
        bf16x8 wl = *(const bf16x8*)(wbA + kb*1024 + 512);
        acc0 = __builtin_amdgcn_mfma_f32_16x16x32_bf16(ah, wh, acc0, 0, 0, 0);
        acc1 = __builtin_amdgcn_mfma_f32_16x16x32_bf16(ah, wl, acc1, 0, 0, 0);
        acc2 = __builtin_amdgcn_mfma_f32_16x16x32_bf16(al, wh, acc2, 0, 0, 0);
        if (nw == 0) { bf16x8 zf = *(const bf16x8*)(wzA + kb*512);
                       az = __builtin_amdgcn_mfma_f32_16x16x32_bf16(ah, zf, az, 0, 0, 0); }
        if (nw == 1) { bf16x8 zf = *(const bf16x8*)(wzA + kb*512);
                       az = __builtin_amdgcn_mfma_f32_16x16x32_bf16(al, zf, az, 0, 0, 0); }
      }
      for (int k4 = 0; k4 < 4; ++k4) {
        int kb = 32 + k4;
        bf16x8 ah = xah[k4], al = xal[k4];
        bf16x8 wh = *(const bf16x8*)(wbA + kb*1024);
        bf16x8 wl = *(const bf16x8*)(wbA + kb*1024 + 512);
        acc0 = __builtin_amdgcn_mfma_f32_16x16x32_bf16(ah, wh, acc0, 0, 0, 0);
        acc1 = __builtin_amdgcn_mfma_f32_16x16x32_bf16(ah, wl, acc1, 0, 0, 0);
        acc2 = __builtin_amdgcn_mfma_f32_16x16x32_bf16(al, wh, acc2, 0, 0, 0);
        if (nw == 0) { bf16x8 zf = *(const bf16x8*)(wzA + kb*512);
                       az = __builtin_amdgcn_mfma_f32_16x16x32_bf16(ah, zf, az, 0, 0, 0); }
        if (nw == 1) { bf16x8 zf = *(const bf16x8*)(wzA + kb*512);
                       az = __builtin_amdgcn_mfma_f32_16x16x32_bf16(al, zf, az, 0, 0, 0); }
      }
      f32x4 accs = acc0 + acc1; accs = accs + acc2;
      int cc = nw*16 + (lane & 15);
      int r0 = (lane >> 4) * 4;
      ls_s[r0+0][cc] = accs[0]; ls_s[r0+1][cc] = accs[1];
      ls_s[r0+2][cc] = accs[2]; ls_s[r0+3][cc] = accs[3];
      if (nw == 0 && (lane&15) == 0) {
        for (int j2 = 0; j2 < 4; ++j2) zp[0][r0+j2] = az[j2];
      }
      if (nw == 0 && (lane&15) == 1) {
        for (int j2 = 0; j2 < 4; ++j2) zp[1][r0+j2] = az[j2];
      }
      if (nw == 1 && (lane&15) == 0) {
        for (int j2 = 0; j2 < 4; ++j2) zp[2][r0+j2] = az[j2];
      }
    }
    __syncthreads();
    {
      // epilogue layer 1 (zb==1); znew computed inline per-thread
      float zs = zp[0][er] + zp[1][er] + zp[2][er] + bz1;
      float zn = fminf(fmaxf((zs + 1.f)*0.5f, 0.f), 1.f);
      float4 sv = *(const float4*)&ls_s[er][4*eu];
      float4 bb = *(const float4*)&bp1[ntg*128 + 4*eu];
      float f = sigmoidf_(sv.x + bb.x);
      float i = sigmoidf_(sv.y + bb.y);
      float o = sigmoidf_(sv.z + bb.z);
      float g = tanhf(sv.w + bb.w);
      float z = z1p;
      float ig = i * g;
      float cn = z * ig + (1.f - z) * fmaf(f, c1r, ig);
      float hn = o * tanhf(cn);
      c1r = cn;
      z1c = zn; z1p = zn;
      u16* a1w = A1b[p ^ 1];
      split_st_uc(a1w + pidx, a1w + PLSTR + pidx, (1.f - zn) * hn);   // A next step
      split_st_uc(B2b + pidx, B2b + PLSTR + pidx, zn * hn);           // B this step
    }
    drain_vmem();      // asm stores are outside the compiler's waitcnt tracking
    __syncthreads();   // all waves' stores at coherence point before arrival
    if (tid == 0) {
      __hip_atomic_fetch_add(cnt, 1u, __ATOMIC_RELAXED, __HIP_MEMORY_SCOPE_AGENT);
      while (__hip_atomic_load(cnt, __ATOMIC_RELAXED, __HIP_MEMORY_SCOPE_AGENT) < bar_tgt)
        __builtin_amdgcn_s_sleep(1);
    }
    bar_tgt += 16u;
    __builtin_amdgcn_s_barrier();

    // ======== PHASE B ========
    for (int j = 0; j < 4; ++j) {   // stage B2 (phase-A writes, fenced by barrier#1)
      int i = nw*4 + j; int spl = i >> 4, kq = i & 15;
      const u16* src = B2b + spl*PLSTR + ((size_t)((kq*4 + kgp)*256 + b0 + row16))*8;
      gload_lds16_uc(src, &stgB[1][spl][kq][0][0]);
    }
    for (int j = 0; j < 4; ++j) {   // prefetch A1[p^1] (phase-A writes, fenced by barrier#1)
      int i = nw*4 + j; int spl = i >> 4, kq = i & 15;
      const u16* src = A1b[p ^ 1] + spl*PLSTR + ((size_t)((kq*4 + kgp)*256 + b0 + row16))*8;
      gload_lds16_uc(src, &stgA[0][spl][kq][0][0]);
    }
    __syncthreads();

    {
      f32x4 acc0={0,0,0,0}, acc1={0,0,0,0}, acc2={0,0,0,0};
      f32x4 az={0,0,0,0};
      #pragma unroll 4
      for (int kb = 0; kb < 32; ++kb) {
        const u16* sa = &stgB[kb>>4][0][kb&15][lane][0];
        bf16x8 ah = *(const bf16x8*)sa;
        bf16x8 al = *(const bf16x8*)(sa + 8192);
        bf16x8 wh = *(const bf16x8*)(wbB + kb*1024);
        bf16x8 wl = *(const bf16x8*)(wbB + kb*1024 + 512);
        acc0 = __builtin_amdgcn_mfma_f32_16x16x32_bf16(ah, wh, acc0, 0, 0, 0);
        acc1 = __builtin_amdgcn_mfma_f32_16x16x32_bf16(ah, wl, acc1, 0, 0, 0);
        acc2 = __builtin_amdgcn_mfma_f32_16x16x32_bf16(al, wh, acc2, 0, 0, 0);
        if (nw == 0) { bf16x8 zf = *(const bf16x8*)(wzB + kb*512);
                       az = __builtin_amdgcn_mfma_f32_16x16x32_bf16(ah, zf, az, 0, 0, 0); }
        if (nw == 1) { bf16x8 zf = *(const bf16x8*)(wzB + kb*512);
                       az = __builtin_amdgcn_mfma_f32_16x16x32_bf16(al, zf, az, 0, 0, 0); }
      }
      f32x4 accs = acc0 + acc1; accs = accs + acc2;
      int cc = nw*16 + (lane & 15);
      int r0 = (lane >> 4) * 4;
      ls_s[r0+0][cc] = accs[0]; ls_s[r0+1][cc] = accs[1];
      ls_s[r0+2][cc] = accs[2]; ls_s[r0+3][cc] = accs[3];
      if (nw == 0 && (lane&15) == 0) {
        for (int j2 = 0; j2 < 4; ++j2) zp[0][r0+j2] = az[j2];
      }
      if (nw == 0 && (lane&15) == 1) {
        for (int j2 = 0; j2 < 4; ++j2) zp[1][r0+j2] = az[j2];
      }
      if (nw == 1 && (lane&15) == 0) {
        for (int j2 = 0; j2 < 4; ++j2) zp[2][r0+j2] = az[j2];
      }
    }
    __syncthreads();
    {
      // epilogue layer 2: z = z2(t-1), zb = z1(t); znew inline
      float zs = zp[0][er] + zp[1][er] + zp[2][er] + bz2;
      float z2n_ = fminf(fmaxf((zs + 1.f)*0.5f, 0.f), 1.f);
      float4 sv = *(const float4*)&ls_s[er][4*eu];
      float4 bb = *(const float4*)&bp2[ntg*128 + 4*eu];
      float f = sigmoidf_(sv.x + bb.x);
      float i = sigmoidf_(sv.y + bb.y);
      float o = sigmoidf_(sv.z + bb.z);
      float g = tanhf(sv.w + bb.w);
      float z = z2p, zb = z1c;
      float ig = i * g;
      float cn = z*ig + (1.f-z)*(1.f-zb)*c2r + (1.f-z)*zb*fmaf(f, c2r, ig);
      float tc = tanhf(cn);
      float ot = o * tc;
      float hn = z*ot + (1.f-z)*(1.f-zb)*h2r + (1.f-z)*zb*ot;
      c2r = cn; h2r = hn;
      z2p = z2n_;
      y[((size_t)erow * TT + t) * HH + ku] = hn * z2n_;
      u16* b1w = B1b[p ^ 1];
      split_st_uc(b1w + pidx, b1w + PLSTR + pidx, (1.f - z2n_) * hn);  // B next step
      split_st_uc(A2b + pidx, A2b + PLSTR + pidx, z1c * hn);           // A next step
    }
    drain_vmem();
    __syncthreads();   // all waves' stores at coherence point before arrival
    if (tid == 0) {
      __hip_atomic_fetch_add(cnt, 1u, __ATOMIC_RELAXED, __HIP_MEMORY_SCOPE_AGENT);
      while (__hip_atomic_load(cnt, __ATOMIC_RELAXED, __HIP_MEMORY_SCOPE_AGENT) < bar_tgt)
        __builtin_amdgcn_s_sleep(1);
    }
    bar_tgt += 16u;
    __builtin_amdgcn_s_barrier();

    p ^= 1;
  }
}

extern "C" void kernel_launch(void* const* d_in, const int* in_sizes, int n_in,
                              void* d_out, int out_size, void* d_ws, size_t ws_size,
                              hipStream_t stream) {
  const float* x     = (const float*)d_in[0];
  const float* U11_1 = (const float*)d_in[1];
  const float* U21_1 = (const float*)d_in[2];
  const float* W01_1 = (const float*)d_in[3];
  const float* b1    = (const float*)d_in[4];
  const float* U11_2 = (const float*)d_in[5];
  const float* W01_2 = (const float*)d_in[6];
  const float* b2    = (const float*)d_in[7];
  char*  wsb = (char*)d_ws;
  float* y   = (float*)d_out;
  (void)in_sizes; (void)n_in; (void)out_size; (void)ws_size;

  u16* wp    = (u16*)(wsb + OFF_WPA);
  u16* wzfa  = (u16*)(wsb + OFF_WZFA);
  u16* wzfb  = (u16*)(wsb + OFF_WZFB);
  float* bp1 = (float*)(wsb + OFF_BP1);
  float* bp2 = (float*)(wsb + OFF_BP2);
  float* bz  = (float*)(wsb + OFF_BZ);

  const unsigned NW = 128u*NKA*2u*512u + 128u*NKB*2u*512u;
  hipLaunchKernelGGL(pack_w, dim3((NW + 255u)/256u), dim3(256), 0, stream,
                     U11_1, U21_1, W01_1, U11_2, W01_2, wp);
  const unsigned NZ = 36u*512u + 32u*512u;
  hipLaunchKernelGGL(pack_wz, dim3((NZ + 255u)/256u), dim3(256), 0, stream,
                     U11_1, U21_1, W01_1, U11_2, W01_2, wzfa, wzfb);
  hipLaunchKernelGGL(pack_bias, dim3(17), dim3(256), 0, stream, b1, b2, bp1, bp2, bz);
  const unsigned n_zero_words = (unsigned)((OFF_END - OFF_CNT) / 4u);
  hipLaunchKernelGGL(init_zero, dim3((n_zero_words + 255u)/256u), dim3(256), 0, stream, wsb);

  const float* xq = x;
  char* wsq = wsb;
  float* yq = y;
  void* kargs[] = { (void*)&xq, (void*)&wsq, (void*)&yq };
  hipLaunchCooperativeKernel((void*)hmlstm_kernel, dim3(256), dim3(512), kargs, 0, stream);
}